// Round 15
// baseline (159.578 us; speedup 1.0000x reference)
//
#include <hip/hip_runtime.h>

typedef unsigned short u16;
typedef unsigned int u32;
typedef float f32x4 __attribute__((ext_vector_type(4)));
typedef short s16x8 __attribute__((ext_vector_type(8)));

#define LSEQ 2048
#define QIN 512
#define VIN 1024
#define KCAT 704
#define KEFF 2560
#define NORMS 0.10206207261596575f  // 1/sqrt(96)

__device__ __forceinline__ u16 f2bf(float f) {
  u32 u = __float_as_uint(f);
  u = (u + 0x7fffu + ((u >> 16) & 1u)) >> 16;  // RNE
  return (u16)u;
}
__device__ __forceinline__ float bf2f(u16 v) {
  return __uint_as_float(((u32)v) << 16);
}

__device__ __forceinline__ s16x8 load8cvt(const float* __restrict__ p) {
  float4 a = *(const float4*)p;
  float4 b = *(const float4*)(p + 4);
  s16x8 r;
  r[0] = (short)f2bf(a.x); r[1] = (short)f2bf(a.y);
  r[2] = (short)f2bf(a.z); r[3] = (short)f2bf(a.w);
  r[4] = (short)f2bf(b.x); r[5] = (short)f2bf(b.y);
  r[6] = (short)f2bf(b.z); r[7] = (short)f2bf(b.w);
  return r;
}

__device__ __forceinline__ s16x8 cvt2x4(float4 a, float4 b) {
  s16x8 r;
  r[0] = (short)f2bf(a.x); r[1] = (short)f2bf(a.y);
  r[2] = (short)f2bf(a.z); r[3] = (short)f2bf(a.w);
  r[4] = (short)f2bf(b.x); r[5] = (short)f2bf(b.y);
  r[6] = (short)f2bf(b.z); r[7] = (short)f2bf(b.w);
  return r;
}

// Fragment-linear index for a weight matrix W[N=96][K]:
// element W[o][k] -> ((kc*6 + nt)*64 + kg*16 + ln)*8 + j
__device__ __forceinline__ size_t wfrag_idx(int o, int k) {
  int kc = k >> 5, kg = (k >> 3) & 3, j = k & 7;
  int nt = o >> 4, ln = o & 15;
  return ((size_t)(kc * 6 + nt) * 64 + kg * 16 + ln) * 8 + j;
}

// ---------------------------------------------------------------------------
// Kernel 1 (prep1): conv-weight transposes (c3t[t][c][j], c5t[t][c][j]),
// q_w/v_w -> frag bf16, k_w conv-slices -> tiny frags kw3f/kw5f, b_eff.
// ---------------------------------------------------------------------------
__global__ __launch_bounds__(256) void prep1(
    const float* __restrict__ q_w, const float* __restrict__ k_w,
    const float* __restrict__ k_b, const float* __restrict__ v_w,
    const float* __restrict__ cn3_w, const float* __restrict__ cn3_b,
    const float* __restrict__ cn5_w, const float* __restrict__ cn5_b,
    float* __restrict__ c3t, float* __restrict__ c5t,
    u16* __restrict__ qwf, u16* __restrict__ vwf,
    u16* __restrict__ kw3f, u16* __restrict__ kw5f,
    float* __restrict__ beff) {
  int blk = blockIdx.x, tid = threadIdx.x;
  if (blk < 576) {                       // c3t: 147456
    int idx = blk * 256 + tid;
    int t = idx / (512 * 96);
    int rem = idx - t * 512 * 96;
    int c = rem / 96, j = rem - c * 96;
    c3t[idx] = cn3_w[(j * 512 + c) * 3 + t];
  } else if (blk < 1536) {               // c5t: 245760
    int idx = (blk - 576) * 256 + tid;
    int t = idx / (512 * 96);
    int rem = idx - t * 512 * 96;
    int c = rem / 96, j = rem - c * 96;
    c5t[idx] = cn5_w[(j * 512 + c) * 5 + t];
  } else if (blk < 1728) {               // qwf: 49152
    int e = (blk - 1536) * 256 + tid;
    int o = e >> 9, k = e & 511;
    qwf[wfrag_idx(o, k)] = f2bf(q_w[e]);
  } else if (blk < 2112) {               // vwf: 98304
    int e = (blk - 1728) * 256 + tid;
    int o = e >> 10, k = e & 1023;
    vwf[wfrag_idx(o, k)] = f2bf(v_w[e]);
  } else if (blk < 2184) {               // kw3f + kw5f: 2*9216
    int e = (blk - 2112) * 256 + tid;
    int half = e / 9216;
    int i = e - half * 9216;
    int o = i / 96, j = i - o * 96;
    float v = k_w[o * KCAT + (half ? 608 : 512) + j];
    size_t di = ((size_t)((j >> 5) * 6 + (o >> 4)) * 64 +
                 ((j >> 3) & 3) * 16 + (o & 15)) * 8 + (j & 7);
    (half ? kw5f : kw3f)[di] = f2bf(v);
  } else {                               // b_eff
    if (tid < 96) {
      const float* kwo = k_w + tid * KCAT;
      float b = k_b[tid];
      for (int j = 0; j < 96; ++j)
        b += kwo[512 + j] * cn3_b[j] + kwo[608 + j] * cn5_b[j];
      beff[tid] = b;
    }
  }
}

// ---------------------------------------------------------------------------
// Kernel 2 (prep2): W_eff fold as a GEMM (M=2560, N=96, K=96).
// ---------------------------------------------------------------------------
__global__ __launch_bounds__(256) void prep2(
    const float* __restrict__ c3t, const float* __restrict__ c5t,
    const u16* __restrict__ kw3f, const u16* __restrict__ kw5f,
    const float* __restrict__ k_w, u16* __restrict__ wefff) {
  __shared__ float Ls[4][16][100];
  int blk = blockIdx.x, tid = threadIdx.x;
  int wid = tid >> 6, lane = tid & 63, ln = lane & 15, kg = lane >> 4;
  int k = blk * 64 + wid * 16 + ln;
  bool c3ok = (k >= 512) && (k < 2048);
  const float* a5 = c5t + (size_t)k * 96;
  const float* a3 = c3t + (size_t)(c3ok ? k - 512 : 0) * 96;
  f32x4 acc[6];
  #pragma unroll
  for (int nt = 0; nt < 6; ++nt) acc[nt] = (f32x4){0.f, 0.f, 0.f, 0.f};
  #pragma unroll
  for (int jc = 0; jc < 3; ++jc) {
    s16x8 aa5 = load8cvt(a5 + jc * 32 + kg * 8);
    s16x8 aa3 = (s16x8){0, 0, 0, 0, 0, 0, 0, 0};
    if (c3ok) aa3 = load8cvt(a3 + jc * 32 + kg * 8);
    const u16* b5 = kw5f + (size_t)jc * 3072 + lane * 8;
    const u16* b3 = kw3f + (size_t)jc * 3072 + lane * 8;
    #pragma unroll
    for (int nt = 0; nt < 6; ++nt) {
      acc[nt] = __builtin_amdgcn_mfma_f32_16x16x32_bf16(
          aa5, *(const s16x8*)&b5[nt * 512], acc[nt], 0, 0, 0);
      acc[nt] = __builtin_amdgcn_mfma_f32_16x16x32_bf16(
          aa3, *(const s16x8*)&b3[nt * 512], acc[nt], 0, 0, 0);
    }
  }
  #pragma unroll
  for (int nt = 0; nt < 6; ++nt)
    #pragma unroll
    for (int r = 0; r < 4; ++r)
      Ls[wid][kg * 4 + r][nt * 16 + ln] = acc[nt][r];
  asm volatile("s_waitcnt lgkmcnt(0)" ::: "memory");
  #pragma unroll
  for (int sl = 0; sl < 3; ++sl) {
    int slot = sl * 64 + lane;
    int o = slot >> 1, rc = slot & 1;
    int k0 = blk * 64 + wid * 16 + rc * 8;
    int t = k0 >> 9, cbase = k0 & 511;
    s16x8 ov;
    #pragma unroll
    for (int e = 0; e < 8; ++e) {
      float v = Ls[wid][rc * 8 + e][o];
      if (t == 2) v += k_w[o * KCAT + cbase + e];
      ov[e] = (short)f2bf(v);
    }
    *(s16x8*)&wefff[((size_t)((k0 >> 5) * 6 + (o >> 4)) * 64 +
                     ((k0 >> 3) & 3) * 16 + (o & 15)) * 8] = ov;
  }
}

// ---------------------------------------------------------------------------
// Kernel 3: Q+K-conv and V projections fused.  QK path NOW OP-SPLIT: wave 0
// computes Q for all 64 rows (4 row-groups), waves 1/2/3 compute conv taps
// {0,1}/{2,3}/{4} for all 64 rows (taps sum in-register).  Each B-fragment
// is read from LDS once per wave and reused by 4 MFMAs -> block LDS reads
// per kcg drop 168 -> 60.  K output reduced across waves 1-3 via Ls.
// grid (64,8): blockIdx.x<32 -> QK path, else V path.  2 blocks/CU.
// ---------------------------------------------------------------------------
__global__ __launch_bounds__(256, 2) void proj_fused(
    const float* __restrict__ evo, const float* __restrict__ plm,
    const u16* __restrict__ qwf, const u16* __restrict__ vwf,
    const u16* __restrict__ wefff, const float* __restrict__ q_b,
    const float* __restrict__ beff, const float* __restrict__ v_b,
    u16* __restrict__ Qf, u16* __restrict__ Kf,
    u16* __restrict__ Vfr, u16* __restrict__ Vb) {
  __shared__ u16 At[2 * 68 * 72];     // 19584 B, A double-buffer
  __shared__ u16 LBS[18432];          // 36864 B, B single-buffer (+ Ls alias)
  float* Ls = (float*)LBS;            // epilogue scratch: [slot*1600 + r*100 + c]
  int bxr = blockIdx.x, bb = blockIdx.y;
  int tid = threadIdx.x;
  int wid = tid >> 6, lane = tid & 63, ln = lane & 15, kg = lane >> 4;
  int srow = tid >> 2, spart = tid & 3;

  if (bxr < 32) {
    // ---------------- QK path (A = evo, 68-row halo tile) ----------------
    int bx = bxr;
    int r0 = bx * 64;
    const float* xb = evo + (size_t)bb * LSEQ * QIN;
    bool halo = tid < 16;
    int hrow = 64 + (tid >> 2);

    float4 ra0, ra1, ra2, ra3, rb0, rb1, rb2, rb3;
    auto LOADS = [&](int s) {
      int g = r0 - 2 + srow;
      if (g >= 0 && g < LSEQ) {
        const float* p = xb + (size_t)g * QIN + s * 64 + spart * 16;
        ra0 = *(const float4*)p;       ra1 = *(const float4*)(p + 4);
        ra2 = *(const float4*)(p + 8); ra3 = *(const float4*)(p + 12);
      } else {
        ra0 = ra1 = ra2 = ra3 = make_float4(0.f, 0.f, 0.f, 0.f);
      }
      if (halo) {
        int g2 = r0 - 2 + hrow;
        if (g2 < LSEQ) {
          const float* p = xb + (size_t)g2 * QIN + s * 64 + spart * 16;
          rb0 = *(const float4*)p;       rb1 = *(const float4*)(p + 4);
          rb2 = *(const float4*)(p + 8); rb3 = *(const float4*)(p + 12);
        } else {
          rb0 = rb1 = rb2 = rb3 = make_float4(0.f, 0.f, 0.f, 0.f);
        }
      }
    };
    auto WRITES = [&](int buf) {
      u16* d = &At[(buf * 68 + srow) * 72 + spart * 16];
      *(s16x8*)d = cvt2x4(ra0, ra1);
      *(s16x8*)(d + 8) = cvt2x4(ra2, ra3);
      if (halo) {
        u16* d2 = &At[(buf * 68 + hrow) * 72 + spart * 16];
        *(s16x8*)d2 = cvt2x4(rb0, rb1);
        *(s16x8*)(d2 + 8) = cvt2x4(rb2, rb3);
      }
    };

    // B staging: 36 KB = [Q, tap0..tap4][kcg slice 6KB]; 9x16B per thread
    s16x8 br[9];
    auto LOADB = [&](int kcg) {
      #pragma unroll
      for (int j = 0; j < 9; ++j) {
        int idx = tid + j * 256;
        int chunk = idx / 384;           // 0=Q, 1..5=taps
        int off = idx - chunk * 384;
        const u16* src = (chunk == 0)
            ? qwf + (size_t)kcg * 3072 + off * 8
            : wefff + (size_t)(chunk - 1) * 49152 + (size_t)kcg * 3072 + off * 8;
        br[j] = *(const s16x8*)src;
      }
    };
    auto STOREB = [&]() {
      #pragma unroll
      for (int j = 0; j < 9; ++j) {
        int idx = tid + j * 256;
        *(s16x8*)&LBS[idx * 8] = br[j];
      }
    };

    // acc[rg][nt]: wave 0 -> Q rows rg*16..; waves 1-3 -> K tap-partials
    f32x4 acc[4][6];
    #pragma unroll
    for (int rg = 0; rg < 4; ++rg)
      #pragma unroll
      for (int nt = 0; nt < 6; ++nt) acc[rg][nt] = (f32x4){0.f, 0.f, 0.f, 0.f};

    int tap0 = (wid == 1) ? 0 : (wid == 2) ? 2 : 4;   // taps for this wave
    int ntap = (wid == 3) ? 1 : 2;

    LOADS(0);
    LOADB(0);
    WRITES(0);
    STOREB();
    __syncthreads();
    int cur = 0;
    for (int s = 0; s < 8; ++s) {
      if (s < 7) LOADS(s + 1);
      #pragma unroll
      for (int cc = 0; cc < 2; ++cc) {
        int kcg = s * 2 + cc;
        bool havenext = kcg < 15;
        if (havenext) LOADB(kcg + 1);
        const u16* abase = &At[(cur * 68 + ln) * 72 + cc * 32 + kg * 8];
        if (wid == 0) {
          // Q for all 4 row-groups; 6 B loads reused 4x
          const u16* lb = LBS + lane * 8;
          s16x8 b0 = *(const s16x8*)&lb[0 * 512];
          s16x8 b1 = *(const s16x8*)&lb[1 * 512];
          s16x8 b2 = *(const s16x8*)&lb[2 * 512];
          s16x8 b3 = *(const s16x8*)&lb[3 * 512];
          s16x8 b4 = *(const s16x8*)&lb[4 * 512];
          s16x8 b5 = *(const s16x8*)&lb[5 * 512];
          #pragma unroll
          for (int rg = 0; rg < 4; ++rg) {
            s16x8 a = *(const s16x8*)&abase[(rg * 16 + 2) * 72];
            acc[rg][0] = __builtin_amdgcn_mfma_f32_16x16x32_bf16(a, b0, acc[rg][0], 0, 0, 0);
            acc[rg][1] = __builtin_amdgcn_mfma_f32_16x16x32_bf16(a, b1, acc[rg][1], 0, 0, 0);
            acc[rg][2] = __builtin_amdgcn_mfma_f32_16x16x32_bf16(a, b2, acc[rg][2], 0, 0, 0);
            acc[rg][3] = __builtin_amdgcn_mfma_f32_16x16x32_bf16(a, b3, acc[rg][3], 0, 0, 0);
            acc[rg][4] = __builtin_amdgcn_mfma_f32_16x16x32_bf16(a, b4, acc[rg][4], 0, 0, 0);
            acc[rg][5] = __builtin_amdgcn_mfma_f32_16x16x32_bf16(a, b5, acc[rg][5], 0, 0, 0);
          }
        } else {
          #pragma unroll
          for (int tt = 0; tt < 2; ++tt) {
            if (tt < ntap) {
              int t = tap0 + tt;
              const u16* lb = LBS + (1 + t) * 3072 + lane * 8;
              s16x8 b0 = *(const s16x8*)&lb[0 * 512];
              s16x8 b1 = *(const s16x8*)&lb[1 * 512];
              s16x8 b2 = *(const s16x8*)&lb[2 * 512];
              s16x8 b3 = *(const s16x8*)&lb[3 * 512];
              s16x8 b4 = *(const s16x8*)&lb[4 * 512];
              s16x8 b5 = *(const s16x8*)&lb[5 * 512];
              #pragma unroll
              for (int rg = 0; rg < 4; ++rg) {
                s16x8 a = *(const s16x8*)&abase[(rg * 16 + t) * 72];
                acc[rg][0] = __builtin_amdgcn_mfma_f32_16x16x32_bf16(a, b0, acc[rg][0], 0, 0, 0);
                acc[rg][1] = __builtin_amdgcn_mfma_f32_16x16x32_bf16(a, b1, acc[rg][1], 0, 0, 0);
                acc[rg][2] = __builtin_amdgcn_mfma_f32_16x16x32_bf16(a, b2, acc[rg][2], 0, 0, 0);
                acc[rg][3] = __builtin_amdgcn_mfma_f32_16x16x32_bf16(a, b3, acc[rg][3], 0, 0, 0);
                acc[rg][4] = __builtin_amdgcn_mfma_f32_16x16x32_bf16(a, b4, acc[rg][4], 0, 0, 0);
                acc[rg][5] = __builtin_amdgcn_mfma_f32_16x16x32_bf16(a, b5, acc[rg][5], 0, 0, 0);
              }
            }
          }
        }
        __syncthreads();                 // everyone done reading LBS
        if (havenext) STOREB();
        if (cc == 1 && s < 7) WRITES(cur ^ 1);
        __syncthreads();                 // B(next) + A(next) published
      }
      if (s < 7) cur ^= 1;
    }

    // epilogue: per row-group, K = sum of waves 1-3 partials, Q from wave 0.
    int slot = (wid == 0) ? 3 : (wid - 1);
    #pragma unroll
    for (int rg = 0; rg < 4; ++rg) {
      if (rg) __syncthreads();
      #pragma unroll
      for (int nt = 0; nt < 6; ++nt)
        #pragma unroll
        for (int r = 0; r < 4; ++r)
          Ls[slot * 1600 + (kg * 4 + r) * 100 + nt * 16 + ln] = acc[rg][nt][r];
      __syncthreads();
      size_t qt = (size_t)bb * 128 + bx * 4 + rg;
      if (tid < 192) {
        int r = tid / 12, cg = tid % 12;
        s16x8 ovk, ovq;
        #pragma unroll
        for (int e = 0; e < 8; ++e) {
          int c = cg * 8 + e;
          float kv = Ls[0 * 1600 + r * 100 + c] + Ls[1 * 1600 + r * 100 + c] +
                     Ls[2 * 1600 + r * 100 + c] + beff[c];
          ovk[e] = (short)f2bf(kv);
          ovq[e] = (short)f2bf(Ls[3 * 1600 + r * 100 + c] + q_b[c]);
        }
        *(s16x8*)&Kf[((qt * 3 + (cg >> 2)) * 64 + (cg & 3) * 16 + r) * 8] = ovk;
        *(s16x8*)&Qf[((qt * 3 + (cg >> 2)) * 64 + (cg & 3) * 16 + r) * 8] = ovq;
      }
    }
  } else {
    // ---------------- V path (A = plm, 64-row tile, K=1024) ----------------
    int bx = bxr - 32;
    const float* xb = plm + ((size_t)bb * LSEQ + bx * 64) * VIN;
    float4 ra0, ra1, ra2, ra3;
    auto LOADS = [&](int s) {
      const float* p = xb + (size_t)srow * VIN + s * 64 + spart * 16;
      ra0 = *(const float4*)p;       ra1 = *(const float4*)(p + 4);
      ra2 = *(const float4*)(p + 8); ra3 = *(const float4*)(p + 12);
    };
    auto WRITES = [&](int buf) {
      u16* d = &At[(buf * 68 + srow) * 72 + spart * 16];
      *(s16x8*)d = cvt2x4(ra0, ra1);
      *(s16x8*)(d + 8) = cvt2x4(ra2, ra3);
    };
    // B staging: 12 KB per s-step (2 kcg, contiguous in vwf); 3x16B/thread
    s16x8 br[3];
    auto LOADB = [&](int s) {
      #pragma unroll
      for (int j = 0; j < 3; ++j) {
        int idx = tid + j * 256;
        br[j] = *(const s16x8*)(vwf + (size_t)s * 6144 + idx * 8);
      }
    };
    auto STOREB = [&]() {
      #pragma unroll
      for (int j = 0; j < 3; ++j) {
        int idx = tid + j * 256;
        *(s16x8*)&LBS[idx * 8] = br[j];
      }
    };

    f32x4 acc[6];
    #pragma unroll
    for (int nt = 0; nt < 6; ++nt) acc[nt] = (f32x4){0.f, 0.f, 0.f, 0.f};

    LOADS(0);
    LOADB(0);
    WRITES(0);
    STOREB();
    __syncthreads();
    int cur = 0;
    for (int s = 0; s < 16; ++s) {
      if (s < 15) {
        LOADS(s + 1);
        LOADB(s + 1);
      }
      #pragma unroll
      for (int cc = 0; cc < 2; ++cc) {
        s16x8 a = *(const s16x8*)&At[(cur * 68 + wid * 16 + ln) * 72 +
                                     cc * 32 + kg * 8];
        const u16* lb = LBS + cc * 3072 + lane * 8;
        s16x8 bfr[6];
        #pragma unroll
        for (int nt = 0; nt < 6; ++nt)
          bfr[nt] = *(const s16x8*)&lb[nt * 512];
        #pragma unroll
        for (int nt = 0; nt < 6; ++nt)
          acc[nt] = __builtin_amdgcn_mfma_f32_16x16x32_bf16(
              a, bfr[nt], acc[nt], 0, 0, 0);
      }
      __syncthreads();                   // done reading LBS + At[cur]
      if (s < 15) {
        STOREB();
        WRITES(cur ^ 1);
      }
      __syncthreads();                   // B(s+1) + A(s+1) published
      if (s < 15) cur ^= 1;
    }

    #pragma unroll
    for (int nt = 0; nt < 6; ++nt)
      #pragma unroll
      for (int r = 0; r < 4; ++r)
        Ls[wid * 1600 + (kg * 4 + r) * 100 + nt * 16 + ln] = acc[nt][r];
    asm volatile("s_waitcnt lgkmcnt(0)" ::: "memory");
    #pragma unroll
    for (int sl = 0; sl < 3; ++sl) {
      int slot = sl * 64 + lane;
      int r = slot / 12, cg = slot % 12;
      s16x8 ov;
      #pragma unroll
      for (int e = 0; e < 8; ++e) {
        int c = cg * 8 + e;
        ov[e] = (short)f2bf(Ls[wid * 1600 + r * 100 + c] + v_b[c]);
      }
      *(s16x8*)&Vb[((size_t)bb * LSEQ + bx * 64 + wid * 16 + r) * 96 + cg * 8] = ov;
    }
    #pragma unroll
    for (int sl = 0; sl < 3; ++sl) {
      int slot = sl * 64 + lane;
      int c = slot >> 1, rc = slot & 1;
      int key0 = bx * 64 + wid * 16 + rc * 8;
      s16x8 fv;
      #pragma unroll
      for (int e = 0; e < 8; ++e)
        fv[e] = (short)f2bf(Ls[wid * 1600 + (rc * 8 + e) * 100 + c] + v_b[c]);
      *(s16x8*)&Vfr[(((size_t)bb * 64 + (key0 >> 5)) * 6 + (c >> 4)) * 512 +
                    (((key0 >> 3) & 3) * 16 + (c & 15)) * 8] = fv;
    }
  }
}

// ---------------------------------------------------------------------------
// Kernel 4: flash attention + "+V" (round-13 proven version).  Batch-
// interleaved bid mapping + K-frag register prefetch + setprio.
// ---------------------------------------------------------------------------
__global__ __launch_bounds__(256, 4) void attn_kernel(
    const u16* __restrict__ Qf, const u16* __restrict__ Kf,
    const u16* __restrict__ Vfr, const u16* __restrict__ Vb,
    const int* __restrict__ seqlen, float* __restrict__ out) {
  __shared__ u16 Ps[4][16][40];
  __shared__ float Cacc[4][16][97];
  __shared__ float Cml[4][16][2];

  int bid = blockIdx.x;
  int bb = (bid >> 3) & 7;
  int bx = ((bid >> 6) << 3) | (bid & 7);
  int tid = threadIdx.x;
  int wid = tid >> 6, lane = tid & 63, ln = lane & 15, kg = lane >> 4;
  int n = seqlen[bb];
  int nkc = (n + 31) >> 5;

  size_t qt = (size_t)bb * 128 + bx;
  s16x8 aQ[3];
  #pragma unroll
  for (int kk = 0; kk < 3; ++kk)
    aQ[kk] = *(const s16x8*)&Qf[((qt * 3 + kk) * 64 + lane) * 8];

  float m[4], lsum[4];
  f32x4 acc[6];
  #pragma unroll
  for (int r = 0; r < 4; ++r) { m[r] = -1e30f; lsum[r] = 0.f; }
  #pragma unroll
  for (int nt = 0; nt < 6; ++nt) acc[nt] = (f32x4){0.f, 0.f, 0.f, 0.f};

  const u16* Kbb = Kf + (size_t)bb * 128 * 1536;
  s16x8 kf[6];
  {
    int k0 = (wid < nkc) ? wid : 0;
    const u16* kp = Kbb + (size_t)k0 * 3072 + lane * 8;
    #pragma unroll
    for (int i = 0; i < 6; ++i) kf[i] = *(const s16x8*)&kp[i * 512];
  }

  for (int kc = wid; kc < nkc; kc += 4) {
    int key0 = kc * 32;
    f32x4 s0 = (f32x4){0.f, 0.f, 0.f, 0.f};
    f32x4 s1 = (f32x4){0.f, 0.f, 0.f, 0.f};
    __builtin_amdgcn_s_setprio(1);
    #pragma unroll
    for (int kk = 0; kk < 3; ++kk) {
      s0 = __builtin_amdgcn_mfma_f32_16x16x32_bf16(aQ[kk], kf[kk], s0, 0, 0, 0);
      s1 = __builtin_amdgcn_mfma_f32_16x16x32_bf16(aQ[kk], kf[3 + kk], s1, 0, 0, 0);
    }
    __builtin_amdgcn_s_setprio(0);

    s16x8 kf2[6];
    {
      int kn = (kc + 4 < nkc) ? kc + 4 : 0;
      const u16* kp = Kbb + (size_t)kn * 3072 + lane * 8;
      #pragma unroll
      for (int i = 0; i < 6; ++i) kf2[i] = *(const s16x8*)&kp[i * 512];
    }

    bool v0 = (key0 + ln) < n;
    bool v1 = (key0 + 16 + ln) < n;
    float sv0[4], sv1[4], mx[4];
    #pragma unroll
    for (int r = 0; r < 4; ++r) {
      sv0[r] = v0 ? s0[r] * NORMS : -1e30f;
      sv1[r] = v1 ? s1[r] * NORMS : -1e30f;
      mx[r] = fmaxf(sv0[r], sv1[r]);
    }
    #pragma unroll
    for (int r = 0; r < 4; ++r) {
      mx[r] = fmaxf(mx[r], __shfl_xor(mx[r], 1, 16));
      mx[r] = fmaxf(mx[r], __shfl_xor(mx[r], 2, 16));
      mx[r] = fmaxf(mx[r], __shfl_xor(mx[r], 4, 16));
      mx[r] = fmaxf(mx[r], __shfl_xor(mx[r], 8, 16));
    }
    float p0[4], p1[4], rs[4];
    bool defer = __all((mx[0] <= m[0] + 8.f) && (mx[1] <= m[1] + 8.f) &&
                       (mx[2] <= m[2] + 8.f) && (mx[3] <= m[3] + 8.f));
    if (defer) {
      #pragma unroll
      for (int r = 0; r < 4; ++r) {
        p0[r] = __expf(sv0[r] - m[r]);
        p1[r] = __expf(sv1[r] - m[r]);
        rs[r] = p0[r] + p1[r];
      }
      #pragma unroll
      for (int r = 0; r < 4; ++r) {
        rs[r] += __shfl_xor(rs[r], 1, 16);
        rs[r] += __shfl_xor(rs[r], 2, 16);
        rs[r] += __shfl_xor(rs[r], 4, 16);
        rs[r] += __shfl_xor(rs[r], 8, 16);
        lsum[r] += rs[r];
      }
    } else {
      float fac[4];
      #pragma unroll
      for (int r = 0; r < 4; ++r) {
        float mn = fmaxf(m[r], mx[r]);
        fac[r] = __expf(m[r] - mn);
        p0[r] = __expf(sv0[r] - mn);
        p1[r] = __expf(sv1[r] - mn);
        rs[r] = p0[r] + p1[r];
        m[r] = mn;
      }
      #pragma unroll
      for (int r = 0; r < 4; ++r) {
        rs[r] += __shfl_xor(rs[r], 1, 16);
        rs[r] += __shfl_xor(rs[r], 2, 16);
        rs[r] += __shfl_xor(rs[r], 4, 16);
        rs[r] += __shfl_xor(rs[r], 8, 16);
        lsum[r] = lsum[r] * fac[r] + rs[r];
      }
      #pragma unroll
      for (int nt = 0; nt < 6; ++nt)
        #pragma unroll
        for (int r = 0; r < 4; ++r) acc[nt][r] *= fac[r];
    }

    u16* Pw = &Ps[wid][0][0];
    #pragma unroll
    for (int r = 0; r < 4; ++r) {
      Pw[(kg * 4 + r) * 40 + ln] = f2bf(p0[r]);
      Pw[(kg * 4 + r) * 40 + 16 + ln] = f2bf(p1[r]);
    }
    s16x8 pa = *(const s16x8*)&Pw[ln * 40 + kg * 8];

    const u16* vf = Vfr + (((size_t)bb * 64 + kc) * 6 * 64) * 8 + lane * 8;
    s16x8 bv[6];
    #pragma unroll
    for (int nt = 0; nt < 6; ++nt)
      bv[nt] = *(const s16x8*)&vf[(size_t)nt * 512];
    __builtin_amdgcn_s_setprio(1);
    #pragma unroll
    for (int nt = 0; nt < 6; ++nt)
      acc[nt] = __builtin_amdgcn_mfma_f32_16x16x32_bf16(pa, bv[nt], acc[nt], 0, 0, 0);
    __builtin_amdgcn_s_setprio(0);
    #pragma unroll
    for (int i = 0; i < 6; ++i) kf[i] = kf2[i];
  }

  #pragma unroll
  for (int nt = 0; nt < 6; ++nt)
    #pragma unroll
    for (int r = 0; r < 4; ++r)
      Cacc[wid][kg * 4 + r][nt * 16 + ln] = acc[nt][r];
  if (ln == 0) {
    #pragma unroll
    for (int r = 0; r < 4; ++r) {
      Cml[wid][kg * 4 + r][0] = m[r];
      Cml[wid][kg * 4 + r][1] = lsum[r];
    }
  }
  __syncthreads();

  size_t obase = ((size_t)bb * LSEQ + bx * 16) * 96;
  for (int i = tid; i < 1536; i += 256) {
    int row = i / 96;
    float mg = -1e30f;
    #pragma unroll
    for (int w = 0; w < 4; ++w) mg = fmaxf(mg, Cml[w][row][0]);
    float lg = 0.f, av = 0.f;
    #pragma unroll
    for (int w = 0; w < 4; ++w) {
      float e = __expf(Cml[w][row][0] - mg);
      lg += Cml[w][row][1] * e;
      av += Cacc[w][row][i - row * 96] * e;
    }
    out[obase + i] = av / lg + bf2f(Vb[obase + i]);
  }
}

// ---------------------------------------------------------------------------
extern "C" void kernel_launch(void* const* d_in, const int* in_sizes, int n_in,
                              void* d_out, int out_size, void* d_ws,
                              size_t ws_size, hipStream_t stream) {
  const float* plm   = (const float*)d_in[0];
  const float* evo   = (const float*)d_in[1];
  const int* seqlen  = (const int*)d_in[2];
  const float* q_w   = (const float*)d_in[3];
  const float* q_b   = (const float*)d_in[4];
  const float* k_w   = (const float*)d_in[5];
  const float* k_b   = (const float*)d_in[6];
  const float* v_w   = (const float*)d_in[7];
  const float* v_b   = (const float*)d_in[8];
  const float* cn3_w = (const float*)d_in[9];
  const float* cn3_b = (const float*)d_in[10];
  const float* cn5_w = (const float*)d_in[11];
  const float* cn5_b = (const float*)d_in[12];

  char* ws = (char*)d_ws;
  u16* wefff  = (u16*)(ws + 0);           // 491520
  float* beff = (float*)(ws + 491520);    // 512
  u16* qwf    = (u16*)(ws + 492032);      // 98304
  u16* vwf    = (u16*)(ws + 590336);      // 196608
  float* c3t  = (float*)(ws + 786944);    // 589824
  float* c5t  = (float*)(ws + 1376768);   // 983040
  u16* kw3f   = (u16*)(ws + 2359808);     // 18432
  u16* kw5f   = (u16*)(ws + 2378240);     // 18432
  u16* Qf     = (u16*)(ws + 2396672);     // 3145728
  u16* Kf     = (u16*)(ws + 5542400);     // 3145728
  u16* Vfr    = (u16*)(ws + 8688128);     // 3145728
  u16* Vb     = (u16*)(ws + 11833856);    // 3145728
  float* out  = (float*)d_out;

  prep1<<<2185, 256, 0, stream>>>(q_w, k_w, k_b, v_w, cn3_w, cn3_b, cn5_w,
                                  cn5_b, c3t, c5t, qwf, vwf, kw3f, kw5f, beff);
  prep2<<<40, 256, 0, stream>>>(c3t, c5t, kw3f, kw5f, k_w, wefff);
  proj_fused<<<dim3(64, 8), 256, 0, stream>>>(evo, plm, qwf, vwf, wefff,
                                              q_b, beff, v_b, Qf, Kf, Vfr, Vb);
  attn_kernel<<<1024, 256, 0, stream>>>(Qf, Kf, Vfr, Vb, seqlen, out);
}

// Round 16
// 85.110 us; speedup vs baseline: 1.8750x; 1.8750x over previous
//
#include <hip/hip_runtime.h>

typedef unsigned short u16;
typedef unsigned int u32;
typedef float f32x4 __attribute__((ext_vector_type(4)));
typedef short s16x8 __attribute__((ext_vector_type(8)));

#define LSEQ 2048
#define QIN 512
#define VIN 1024
#define KCAT 704
#define KEFF 2560
#define NORMS 0.10206207261596575f  // 1/sqrt(96)

__device__ __forceinline__ u16 f2bf(float f) {
  u32 u = __float_as_uint(f);
  u = (u + 0x7fffu + ((u >> 16) & 1u)) >> 16;  // RNE
  return (u16)u;
}
__device__ __forceinline__ float bf2f(u16 v) {
  return __uint_as_float(((u32)v) << 16);
}

__device__ __forceinline__ s16x8 load8cvt(const float* __restrict__ p) {
  float4 a = *(const float4*)p;
  float4 b = *(const float4*)(p + 4);
  s16x8 r;
  r[0] = (short)f2bf(a.x); r[1] = (short)f2bf(a.y);
  r[2] = (short)f2bf(a.z); r[3] = (short)f2bf(a.w);
  r[4] = (short)f2bf(b.x); r[5] = (short)f2bf(b.y);
  r[6] = (short)f2bf(b.z); r[7] = (short)f2bf(b.w);
  return r;
}

__device__ __forceinline__ s16x8 cvt2x4(float4 a, float4 b) {
  s16x8 r;
  r[0] = (short)f2bf(a.x); r[1] = (short)f2bf(a.y);
  r[2] = (short)f2bf(a.z); r[3] = (short)f2bf(a.w);
  r[4] = (short)f2bf(b.x); r[5] = (short)f2bf(b.y);
  r[6] = (short)f2bf(b.z); r[7] = (short)f2bf(b.w);
  return r;
}

// Fragment-linear index for a weight matrix W[N=96][K]:
// element W[o][k] -> ((kc*6 + nt)*64 + kg*16 + ln)*8 + j
__device__ __forceinline__ size_t wfrag_idx(int o, int k) {
  int kc = k >> 5, kg = (k >> 3) & 3, j = k & 7;
  int nt = o >> 4, ln = o & 15;
  return ((size_t)(kc * 6 + nt) * 64 + kg * 16 + ln) * 8 + j;
}

// ---------------------------------------------------------------------------
// Kernel 1 (prep1): conv-weight transposes (c3t[t][c][j], c5t[t][c][j]),
// q_w/v_w -> frag bf16, k_w conv-slices -> tiny frags kw3f/kw5f, b_eff.
// ---------------------------------------------------------------------------
__global__ __launch_bounds__(256) void prep1(
    const float* __restrict__ q_w, const float* __restrict__ k_w,
    const float* __restrict__ k_b, const float* __restrict__ v_w,
    const float* __restrict__ cn3_w, const float* __restrict__ cn3_b,
    const float* __restrict__ cn5_w, const float* __restrict__ cn5_b,
    float* __restrict__ c3t, float* __restrict__ c5t,
    u16* __restrict__ qwf, u16* __restrict__ vwf,
    u16* __restrict__ kw3f, u16* __restrict__ kw5f,
    float* __restrict__ beff) {
  int blk = blockIdx.x, tid = threadIdx.x;
  if (blk < 576) {                       // c3t: 147456
    int idx = blk * 256 + tid;
    int t = idx / (512 * 96);
    int rem = idx - t * 512 * 96;
    int c = rem / 96, j = rem - c * 96;
    c3t[idx] = cn3_w[(j * 512 + c) * 3 + t];
  } else if (blk < 1536) {               // c5t: 245760
    int idx = (blk - 576) * 256 + tid;
    int t = idx / (512 * 96);
    int rem = idx - t * 512 * 96;
    int c = rem / 96, j = rem - c * 96;
    c5t[idx] = cn5_w[(j * 512 + c) * 5 + t];
  } else if (blk < 1728) {               // qwf: 49152
    int e = (blk - 1536) * 256 + tid;
    int o = e >> 9, k = e & 511;
    qwf[wfrag_idx(o, k)] = f2bf(q_w[e]);
  } else if (blk < 2112) {               // vwf: 98304
    int e = (blk - 1728) * 256 + tid;
    int o = e >> 10, k = e & 1023;
    vwf[wfrag_idx(o, k)] = f2bf(v_w[e]);
  } else if (blk < 2184) {               // kw3f + kw5f: 2*9216
    int e = (blk - 2112) * 256 + tid;
    int half = e / 9216;
    int i = e - half * 9216;
    int o = i / 96, j = i - o * 96;
    float v = k_w[o * KCAT + (half ? 608 : 512) + j];
    size_t di = ((size_t)((j >> 5) * 6 + (o >> 4)) * 64 +
                 ((j >> 3) & 3) * 16 + (o & 15)) * 8 + (j & 7);
    (half ? kw5f : kw3f)[di] = f2bf(v);
  } else {                               // b_eff
    if (tid < 96) {
      const float* kwo = k_w + tid * KCAT;
      float b = k_b[tid];
      for (int j = 0; j < 96; ++j)
        b += kwo[512 + j] * cn3_b[j] + kwo[608 + j] * cn5_b[j];
      beff[tid] = b;
    }
  }
}

// ---------------------------------------------------------------------------
// Kernel 2 (prep2): W_eff fold as a GEMM (M=2560, N=96, K=96).
// ---------------------------------------------------------------------------
__global__ __launch_bounds__(256) void prep2(
    const float* __restrict__ c3t, const float* __restrict__ c5t,
    const u16* __restrict__ kw3f, const u16* __restrict__ kw5f,
    const float* __restrict__ k_w, u16* __restrict__ wefff) {
  __shared__ float Ls[4][16][100];
  int blk = blockIdx.x, tid = threadIdx.x;
  int wid = tid >> 6, lane = tid & 63, ln = lane & 15, kg = lane >> 4;
  int k = blk * 64 + wid * 16 + ln;
  bool c3ok = (k >= 512) && (k < 2048);
  const float* a5 = c5t + (size_t)k * 96;
  const float* a3 = c3t + (size_t)(c3ok ? k - 512 : 0) * 96;
  f32x4 acc[6];
  #pragma unroll
  for (int nt = 0; nt < 6; ++nt) acc[nt] = (f32x4){0.f, 0.f, 0.f, 0.f};
  #pragma unroll
  for (int jc = 0; jc < 3; ++jc) {
    s16x8 aa5 = load8cvt(a5 + jc * 32 + kg * 8);
    s16x8 aa3 = (s16x8){0, 0, 0, 0, 0, 0, 0, 0};
    if (c3ok) aa3 = load8cvt(a3 + jc * 32 + kg * 8);
    const u16* b5 = kw5f + (size_t)jc * 3072 + lane * 8;
    const u16* b3 = kw3f + (size_t)jc * 3072 + lane * 8;
    #pragma unroll
    for (int nt = 0; nt < 6; ++nt) {
      acc[nt] = __builtin_amdgcn_mfma_f32_16x16x32_bf16(
          aa5, *(const s16x8*)&b5[nt * 512], acc[nt], 0, 0, 0);
      acc[nt] = __builtin_amdgcn_mfma_f32_16x16x32_bf16(
          aa3, *(const s16x8*)&b3[nt * 512], acc[nt], 0, 0, 0);
    }
  }
  #pragma unroll
  for (int nt = 0; nt < 6; ++nt)
    #pragma unroll
    for (int r = 0; r < 4; ++r)
      Ls[wid][kg * 4 + r][nt * 16 + ln] = acc[nt][r];
  asm volatile("s_waitcnt lgkmcnt(0)" ::: "memory");
  #pragma unroll
  for (int sl = 0; sl < 3; ++sl) {
    int slot = sl * 64 + lane;
    int o = slot >> 1, rc = slot & 1;
    int k0 = blk * 64 + wid * 16 + rc * 8;
    int t = k0 >> 9, cbase = k0 & 511;
    s16x8 ov;
    #pragma unroll
    for (int e = 0; e < 8; ++e) {
      float v = Ls[wid][rc * 8 + e][o];
      if (t == 2) v += k_w[o * KCAT + cbase + e];
      ov[e] = (short)f2bf(v);
    }
    *(s16x8*)&wefff[((size_t)((k0 >> 5) * 6 + (o >> 4)) * 64 +
                     ((k0 >> 3) & 3) * 16 + (o & 15)) * 8] = ov;
  }
}

// ---------------------------------------------------------------------------
// Kernel 3: Q+K-conv and V projections fused (round-11/13 proven structure).
// B-panel staged through LDS once per block per kcg, shared by all 4 waves.
// grid (64,8): blockIdx.x<32 -> QK path, else V path.  2 blocks/CU.
// ---------------------------------------------------------------------------
__global__ __launch_bounds__(256, 2) void proj_fused(
    const float* __restrict__ evo, const float* __restrict__ plm,
    const u16* __restrict__ qwf, const u16* __restrict__ vwf,
    const u16* __restrict__ wefff, const float* __restrict__ q_b,
    const float* __restrict__ beff, const float* __restrict__ v_b,
    u16* __restrict__ Qf, u16* __restrict__ Kf,
    u16* __restrict__ Vfr, u16* __restrict__ Vb) {
  __shared__ u16 At[2 * 68 * 72];     // 19584 B, A double-buffer
  __shared__ u16 LBS[18432];          // 36864 B, B single-buffer (+ Ls alias)
  float* Ls = (float*)LBS;            // epilogue scratch: [wid*1600 + r*100 + c]
  int bxr = blockIdx.x, bb = blockIdx.y;
  int tid = threadIdx.x;
  int wid = tid >> 6, lane = tid & 63, ln = lane & 15, kg = lane >> 4;
  int srow = tid >> 2, spart = tid & 3;

  if (bxr < 32) {
    // ---------------- QK path (A = evo, 68-row halo tile) ----------------
    int bx = bxr;
    int r0 = bx * 64;
    const float* xb = evo + (size_t)bb * LSEQ * QIN;
    bool halo = tid < 16;
    int hrow = 64 + (tid >> 2);

    float4 ra0, ra1, ra2, ra3, rb0, rb1, rb2, rb3;
    auto LOADS = [&](int s) {
      int g = r0 - 2 + srow;
      if (g >= 0 && g < LSEQ) {
        const float* p = xb + (size_t)g * QIN + s * 64 + spart * 16;
        ra0 = *(const float4*)p;       ra1 = *(const float4*)(p + 4);
        ra2 = *(const float4*)(p + 8); ra3 = *(const float4*)(p + 12);
      } else {
        ra0 = ra1 = ra2 = ra3 = make_float4(0.f, 0.f, 0.f, 0.f);
      }
      if (halo) {
        int g2 = r0 - 2 + hrow;
        if (g2 < LSEQ) {
          const float* p = xb + (size_t)g2 * QIN + s * 64 + spart * 16;
          rb0 = *(const float4*)p;       rb1 = *(const float4*)(p + 4);
          rb2 = *(const float4*)(p + 8); rb3 = *(const float4*)(p + 12);
        } else {
          rb0 = rb1 = rb2 = rb3 = make_float4(0.f, 0.f, 0.f, 0.f);
        }
      }
    };
    auto WRITES = [&](int buf) {
      u16* d = &At[(buf * 68 + srow) * 72 + spart * 16];
      *(s16x8*)d = cvt2x4(ra0, ra1);
      *(s16x8*)(d + 8) = cvt2x4(ra2, ra3);
      if (halo) {
        u16* d2 = &At[(buf * 68 + hrow) * 72 + spart * 16];
        *(s16x8*)d2 = cvt2x4(rb0, rb1);
        *(s16x8*)(d2 + 8) = cvt2x4(rb2, rb3);
      }
    };

    // B staging: 36 KB = [Q, tap0..tap4][kcg slice 6KB]; 9x16B per thread
    s16x8 br[9];
    auto LOADB = [&](int kcg) {
      #pragma unroll
      for (int j = 0; j < 9; ++j) {
        int idx = tid + j * 256;
        int chunk = idx / 384;           // 0=Q, 1..5=taps
        int off = idx - chunk * 384;
        const u16* src = (chunk == 0)
            ? qwf + (size_t)kcg * 3072 + off * 8
            : wefff + (size_t)(chunk - 1) * 49152 + (size_t)kcg * 3072 + off * 8;
        br[j] = *(const s16x8*)src;
      }
    };
    auto STOREB = [&]() {
      #pragma unroll
      for (int j = 0; j < 9; ++j) {
        int idx = tid + j * 256;
        *(s16x8*)&LBS[idx * 8] = br[j];
      }
    };

    f32x4 accQ[6], accK[6];
    #pragma unroll
    for (int nt = 0; nt < 6; ++nt) {
      accQ[nt] = (f32x4){0.f, 0.f, 0.f, 0.f};
      accK[nt] = (f32x4){0.f, 0.f, 0.f, 0.f};
    }

    LOADS(0);
    LOADB(0);
    WRITES(0);
    STOREB();
    __syncthreads();
    int cur = 0;
    for (int s = 0; s < 8; ++s) {
      if (s < 7) LOADS(s + 1);
      #pragma unroll
      for (int cc = 0; cc < 2; ++cc) {
        int kcg = s * 2 + cc;
        bool havenext = kcg < 15;
        if (havenext) LOADB(kcg + 1);
        const u16* arow = &At[(cur * 68 + wid * 16 + ln) * 72 + cc * 32 + kg * 8];
        s16x8 aQ  = *(const s16x8*)&arow[2 * 72];
        s16x8 aK0 = *(const s16x8*)&arow[0];
        s16x8 aK1 = *(const s16x8*)&arow[1 * 72];
        s16x8 aK3 = *(const s16x8*)&arow[3 * 72];
        s16x8 aK4 = *(const s16x8*)&arow[4 * 72];
        const u16* lb = LBS + lane * 8;
        s16x8 bfr[6];
        #pragma unroll
        for (int i = 0; i < 6; ++i)
          bfr[i] = *(const s16x8*)&lb[i * 512];
        #pragma unroll
        for (int i = 0; i < 6; ++i)
          accQ[i] = __builtin_amdgcn_mfma_f32_16x16x32_bf16(
              aQ, bfr[i], accQ[i], 0, 0, 0);
        #pragma unroll
        for (int t = 0; t < 5; ++t) {
          s16x8 bf2[6];
          #pragma unroll
          for (int i = 0; i < 6; ++i)
            bf2[i] = *(const s16x8*)&lb[(1 + t) * 3072 + i * 512];
          s16x8 aK = (t == 0) ? aK0 : (t == 1) ? aK1 : (t == 2) ? aQ
                   : (t == 3) ? aK3 : aK4;
          #pragma unroll
          for (int i = 0; i < 6; ++i)
            accK[i] = __builtin_amdgcn_mfma_f32_16x16x32_bf16(
                aK, bf2[i], accK[i], 0, 0, 0);
        }
        __syncthreads();                 // everyone done reading LBS
        if (havenext) STOREB();
        if (cc == 1 && s < 7) WRITES(cur ^ 1);
        __syncthreads();                 // B(next) + A(next) published
      }
      if (s < 7) cur ^= 1;
    }

    size_t qt = (size_t)bb * 128 + bx * 4 + wid;
    #pragma unroll
    for (int nt = 0; nt < 6; ++nt)
      #pragma unroll
      for (int r = 0; r < 4; ++r)
        Ls[wid * 1600 + (kg * 4 + r) * 100 + nt * 16 + ln] = accQ[nt][r];
    asm volatile("s_waitcnt lgkmcnt(0)" ::: "memory");
    #pragma unroll
    for (int sl = 0; sl < 3; ++sl) {
      int slot = sl * 64 + lane;
      int r = slot / 12, cg = slot % 12;
      s16x8 ov;
      #pragma unroll
      for (int e = 0; e < 8; ++e) {
        int c = cg * 8 + e;
        ov[e] = (short)f2bf(Ls[wid * 1600 + r * 100 + c] + q_b[c]);
      }
      *(s16x8*)&Qf[((qt * 3 + (cg >> 2)) * 64 + (cg & 3) * 16 + r) * 8] = ov;
    }
    asm volatile("s_waitcnt lgkmcnt(0) vmcnt(0)" ::: "memory");
    #pragma unroll
    for (int nt = 0; nt < 6; ++nt)
      #pragma unroll
      for (int r = 0; r < 4; ++r)
        Ls[wid * 1600 + (kg * 4 + r) * 100 + nt * 16 + ln] = accK[nt][r];
    asm volatile("s_waitcnt lgkmcnt(0)" ::: "memory");
    #pragma unroll
    for (int sl = 0; sl < 3; ++sl) {
      int slot = sl * 64 + lane;
      int r = slot / 12, cg = slot % 12;
      s16x8 ov;
      #pragma unroll
      for (int e = 0; e < 8; ++e) {
        int c = cg * 8 + e;
        ov[e] = (short)f2bf(Ls[wid * 1600 + r * 100 + c] + beff[c]);
      }
      *(s16x8*)&Kf[((qt * 3 + (cg >> 2)) * 64 + (cg & 3) * 16 + r) * 8] = ov;
    }
  } else {
    // ---------------- V path (A = plm, 64-row tile, K=1024) ----------------
    int bx = bxr - 32;
    const float* xb = plm + ((size_t)bb * LSEQ + bx * 64) * VIN;
    float4 ra0, ra1, ra2, ra3;
    auto LOADS = [&](int s) {
      const float* p = xb + (size_t)srow * VIN + s * 64 + spart * 16;
      ra0 = *(const float4*)p;       ra1 = *(const float4*)(p + 4);
      ra2 = *(const float4*)(p + 8); ra3 = *(const float4*)(p + 12);
    };
    auto WRITES = [&](int buf) {
      u16* d = &At[(buf * 68 + srow) * 72 + spart * 16];
      *(s16x8*)d = cvt2x4(ra0, ra1);
      *(s16x8*)(d + 8) = cvt2x4(ra2, ra3);
    };
    // B staging: 12 KB per s-step (2 kcg, contiguous in vwf); 3x16B/thread
    s16x8 br[3];
    auto LOADB = [&](int s) {
      #pragma unroll
      for (int j = 0; j < 3; ++j) {
        int idx = tid + j * 256;
        br[j] = *(const s16x8*)(vwf + (size_t)s * 6144 + idx * 8);
      }
    };
    auto STOREB = [&]() {
      #pragma unroll
      for (int j = 0; j < 3; ++j) {
        int idx = tid + j * 256;
        *(s16x8*)&LBS[idx * 8] = br[j];
      }
    };

    f32x4 acc[6];
    #pragma unroll
    for (int nt = 0; nt < 6; ++nt) acc[nt] = (f32x4){0.f, 0.f, 0.f, 0.f};

    LOADS(0);
    LOADB(0);
    WRITES(0);
    STOREB();
    __syncthreads();
    int cur = 0;
    for (int s = 0; s < 16; ++s) {
      if (s < 15) {
        LOADS(s + 1);
        LOADB(s + 1);
      }
      #pragma unroll
      for (int cc = 0; cc < 2; ++cc) {
        s16x8 a = *(const s16x8*)&At[(cur * 68 + wid * 16 + ln) * 72 +
                                     cc * 32 + kg * 8];
        const u16* lb = LBS + cc * 3072 + lane * 8;
        s16x8 bfr[6];
        #pragma unroll
        for (int nt = 0; nt < 6; ++nt)
          bfr[nt] = *(const s16x8*)&lb[nt * 512];
        #pragma unroll
        for (int nt = 0; nt < 6; ++nt)
          acc[nt] = __builtin_amdgcn_mfma_f32_16x16x32_bf16(
              a, bfr[nt], acc[nt], 0, 0, 0);
      }
      __syncthreads();                   // done reading LBS + At[cur]
      if (s < 15) {
        STOREB();
        WRITES(cur ^ 1);
      }
      __syncthreads();                   // B(s+1) + A(s+1) published
      if (s < 15) cur ^= 1;
    }

    #pragma unroll
    for (int nt = 0; nt < 6; ++nt)
      #pragma unroll
      for (int r = 0; r < 4; ++r)
        Ls[wid * 1600 + (kg * 4 + r) * 100 + nt * 16 + ln] = acc[nt][r];
    asm volatile("s_waitcnt lgkmcnt(0)" ::: "memory");
    #pragma unroll
    for (int sl = 0; sl < 3; ++sl) {
      int slot = sl * 64 + lane;
      int r = slot / 12, cg = slot % 12;
      s16x8 ov;
      #pragma unroll
      for (int e = 0; e < 8; ++e) {
        int c = cg * 8 + e;
        ov[e] = (short)f2bf(Ls[wid * 1600 + r * 100 + c] + v_b[c]);
      }
      *(s16x8*)&Vb[((size_t)bb * LSEQ + bx * 64 + wid * 16 + r) * 96 + cg * 8] = ov;
    }
    #pragma unroll
    for (int sl = 0; sl < 3; ++sl) {
      int slot = sl * 64 + lane;
      int c = slot >> 1, rc = slot & 1;
      int key0 = bx * 64 + wid * 16 + rc * 8;
      s16x8 fv;
      #pragma unroll
      for (int e = 0; e < 8; ++e)
        fv[e] = (short)f2bf(Ls[wid * 1600 + (rc * 8 + e) * 100 + c] + v_b[c]);
      *(s16x8*)&Vfr[(((size_t)bb * 64 + (key0 >> 5)) * 6 + (c >> 4)) * 512 +
                    (((key0 >> 3) & 3) * 16 + (c & 15)) * 8] = fv;
    }
  }
}

// ---------------------------------------------------------------------------
// Kernel 4: flash attention + "+V".  Batch-interleaved bid mapping + K-frag
// register prefetch + T5 setprio around MFMA clusters.
// ---------------------------------------------------------------------------
__global__ __launch_bounds__(256, 4) void attn_kernel(
    const u16* __restrict__ Qf, const u16* __restrict__ Kf,
    const u16* __restrict__ Vfr, const u16* __restrict__ Vb,
    const int* __restrict__ seqlen, float* __restrict__ out) {
  __shared__ u16 Ps[4][16][40];
  __shared__ float Cacc[4][16][97];
  __shared__ float Cml[4][16][2];

  int bid = blockIdx.x;
  int bb = (bid >> 3) & 7;
  int bx = ((bid >> 6) << 3) | (bid & 7);
  int tid = threadIdx.x;
  int wid = tid >> 6, lane = tid & 63, ln = lane & 15, kg = lane >> 4;
  int n = seqlen[bb];
  int nkc = (n + 31) >> 5;

  size_t qt = (size_t)bb * 128 + bx;
  s16x8 aQ[3];
  #pragma unroll
  for (int kk = 0; kk < 3; ++kk)
    aQ[kk] = *(const s16x8*)&Qf[((qt * 3 + kk) * 64 + lane) * 8];

  float m[4], lsum[4];
  f32x4 acc[6];
  #pragma unroll
  for (int r = 0; r < 4; ++r) { m[r] = -1e30f; lsum[r] = 0.f; }
  #pragma unroll
  for (int nt = 0; nt < 6; ++nt) acc[nt] = (f32x4){0.f, 0.f, 0.f, 0.f};

  const u16* Kbb = Kf + (size_t)bb * 128 * 1536;
  s16x8 kf[6];
  {
    int k0 = (wid < nkc) ? wid : 0;
    const u16* kp = Kbb + (size_t)k0 * 3072 + lane * 8;
    #pragma unroll
    for (int i = 0; i < 6; ++i) kf[i] = *(const s16x8*)&kp[i * 512];
  }

  for (int kc = wid; kc < nkc; kc += 4) {
    int key0 = kc * 32;
    f32x4 s0 = (f32x4){0.f, 0.f, 0.f, 0.f};
    f32x4 s1 = (f32x4){0.f, 0.f, 0.f, 0.f};
    __builtin_amdgcn_s_setprio(1);
    #pragma unroll
    for (int kk = 0; kk < 3; ++kk) {
      s0 = __builtin_amdgcn_mfma_f32_16x16x32_bf16(aQ[kk], kf[kk], s0, 0, 0, 0);
      s1 = __builtin_amdgcn_mfma_f32_16x16x32_bf16(aQ[kk], kf[3 + kk], s1, 0, 0, 0);
    }
    __builtin_amdgcn_s_setprio(0);

    s16x8 kf2[6];
    {
      int kn = (kc + 4 < nkc) ? kc + 4 : 0;
      const u16* kp = Kbb + (size_t)kn * 3072 + lane * 8;
      #pragma unroll
      for (int i = 0; i < 6; ++i) kf2[i] = *(const s16x8*)&kp[i * 512];
    }

    bool v0 = (key0 + ln) < n;
    bool v1 = (key0 + 16 + ln) < n;
    float sv0[4], sv1[4], mx[4];
    #pragma unroll
    for (int r = 0; r < 4; ++r) {
      sv0[r] = v0 ? s0[r] * NORMS : -1e30f;
      sv1[r] = v1 ? s1[r] * NORMS : -1e30f;
      mx[r] = fmaxf(sv0[r], sv1[r]);
    }
    #pragma unroll
    for (int r = 0; r < 4; ++r) {
      mx[r] = fmaxf(mx[r], __shfl_xor(mx[r], 1, 16));
      mx[r] = fmaxf(mx[r], __shfl_xor(mx[r], 2, 16));
      mx[r] = fmaxf(mx[r], __shfl_xor(mx[r], 4, 16));
      mx[r] = fmaxf(mx[r], __shfl_xor(mx[r], 8, 16));
    }
    float p0[4], p1[4], rs[4];
    bool defer = __all((mx[0] <= m[0] + 8.f) && (mx[1] <= m[1] + 8.f) &&
                       (mx[2] <= m[2] + 8.f) && (mx[3] <= m[3] + 8.f));
    if (defer) {
      #pragma unroll
      for (int r = 0; r < 4; ++r) {
        p0[r] = __expf(sv0[r] - m[r]);
        p1[r] = __expf(sv1[r] - m[r]);
        rs[r] = p0[r] + p1[r];
      }
      #pragma unroll
      for (int r = 0; r < 4; ++r) {
        rs[r] += __shfl_xor(rs[r], 1, 16);
        rs[r] += __shfl_xor(rs[r], 2, 16);
        rs[r] += __shfl_xor(rs[r], 4, 16);
        rs[r] += __shfl_xor(rs[r], 8, 16);
        lsum[r] += rs[r];
      }
    } else {
      float fac[4];
      #pragma unroll
      for (int r = 0; r < 4; ++r) {
        float mn = fmaxf(m[r], mx[r]);
        fac[r] = __expf(m[r] - mn);
        p0[r] = __expf(sv0[r] - mn);
        p1[r] = __expf(sv1[r] - mn);
        rs[r] = p0[r] + p1[r];
        m[r] = mn;
      }
      #pragma unroll
      for (int r = 0; r < 4; ++r) {
        rs[r] += __shfl_xor(rs[r], 1, 16);
        rs[r] += __shfl_xor(rs[r], 2, 16);
        rs[r] += __shfl_xor(rs[r], 4, 16);
        rs[r] += __shfl_xor(rs[r], 8, 16);
        lsum[r] = lsum[r] * fac[r] + rs[r];
      }
      #pragma unroll
      for (int nt = 0; nt < 6; ++nt)
        #pragma unroll
        for (int r = 0; r < 4; ++r) acc[nt][r] *= fac[r];
    }

    u16* Pw = &Ps[wid][0][0];
    #pragma unroll
    for (int r = 0; r < 4; ++r) {
      Pw[(kg * 4 + r) * 40 + ln] = f2bf(p0[r]);
      Pw[(kg * 4 + r) * 40 + 16 + ln] = f2bf(p1[r]);
    }
    s16x8 pa = *(const s16x8*)&Pw[ln * 40 + kg * 8];

    const u16* vf = Vfr + (((size_t)bb * 64 + kc) * 6 * 64) * 8 + lane * 8;
    s16x8 bv[6];
    #pragma unroll
    for (int nt = 0; nt < 6; ++nt)
      bv[nt] = *(const s16x8*)&vf[(size_t)nt * 512];
    __builtin_amdgcn_s_setprio(1);
    #pragma unroll
    for (int nt = 0; nt < 6; ++nt)
      acc[nt] = __builtin_amdgcn_mfma_f32_16x16x32_bf16(pa, bv[nt], acc[nt], 0, 0, 0);
    __builtin_amdgcn_s_setprio(0);
    #pragma unroll
    for (int i = 0; i < 6; ++i) kf[i] = kf2[i];
  }

  #pragma unroll
  for (int nt = 0; nt < 6; ++nt)
    #pragma unroll
    for (int r = 0; r < 4; ++r)
      Cacc[wid][kg * 4 + r][nt * 16 + ln] = acc[nt][r];
  if (ln == 0) {
    #pragma unroll
    for (int r = 0; r < 4; ++r) {
      Cml[wid][kg * 4 + r][0] = m[r];
      Cml[wid][kg * 4 + r][1] = lsum[r];
    }
  }
  __syncthreads();

  size_t obase = ((size_t)bb * LSEQ + bx * 16) * 96;
  for (int i = tid; i < 1536; i += 256) {
    int row = i / 96;
    float mg = -1e30f;
    #pragma unroll
    for (int w = 0; w < 4; ++w) mg = fmaxf(mg, Cml[w][row][0]);
    float lg = 0.f, av = 0.f;
    #pragma unroll
    for (int w = 0; w < 4; ++w) {
      float e = __expf(Cml[w][row][0] - mg);
      lg += Cml[w][row][1] * e;
      av += Cacc[w][row][i - row * 96] * e;
    }
    out[obase + i] = av / lg + bf2f(Vb[obase + i]);
  }
}

// ---------------------------------------------------------------------------
extern "C" void kernel_launch(void* const* d_in, const int* in_sizes, int n_in,
                              void* d_out, int out_size, void* d_ws,
                              size_t ws_size, hipStream_t stream) {
  const float* plm   = (const float*)d_in[0];
  const float* evo   = (const float*)d_in[1];
  const int* seqlen  = (const int*)d_in[2];
  const float* q_w   = (const float*)d_in[3];
  const float* q_b   = (const float*)d_in[4];
  const float* k_w   = (const float*)d_in[5];
  const float* k_b   = (const float*)d_in[6];
  const float* v_w   = (const float*)d_in[7];
  const float* v_b   = (const float*)d_in[8];
  const float* cn3_w = (const float*)d_in[9];
  const float* cn3_b = (const float*)d_in[10];
  const float* cn5_w = (const float*)d_in[11];
  const float* cn5_b = (const float*)d_in[12];

  char* ws = (char*)d_ws;
  u16* wefff  = (u16*)(ws + 0);           // 491520
  float* beff = (float*)(ws + 491520);    // 512
  u16* qwf    = (u16*)(ws + 492032);      // 98304
  u16* vwf    = (u16*)(ws + 590336);      // 196608
  float* c3t  = (float*)(ws + 786944);    // 589824
  float* c5t  = (float*)(ws + 1376768);   // 983040
  u16* kw3f   = (u16*)(ws + 2359808);     // 18432
  u16* kw5f   = (u16*)(ws + 2378240);     // 18432
  u16* Qf     = (u16*)(ws + 2396672);     // 3145728
  u16* Kf     = (u16*)(ws + 5542400);     // 3145728
  u16* Vfr    = (u16*)(ws + 8688128);     // 3145728
  u16* Vb     = (u16*)(ws + 11833856);    // 3145728
  float* out  = (float*)d_out;

  prep1<<<2185, 256, 0, stream>>>(q_w, k_w, k_b, v_w, cn3_w, cn3_b, cn5_w,
                                  cn5_b, c3t, c5t, qwf, vwf, kw3f, kw5f, beff);
  prep2<<<40, 256, 0, stream>>>(c3t, c5t, kw3f, kw5f, k_w, wefff);
  proj_fused<<<dim3(64, 8), 256, 0, stream>>>(evo, plm, qwf, vwf, wefff,
                                              q_b, beff, v_b, Qf, Kf, Vfr, Vb);
  attn_kernel<<<1024, 256, 0, stream>>>(Qf, Kf, Vfr, Vb, seqlen, out);
}

// Round 17
// 82.764 us; speedup vs baseline: 1.9281x; 1.0284x over previous
//
#include <hip/hip_runtime.h>

typedef unsigned short u16;
typedef unsigned int u32;
typedef float f32x4 __attribute__((ext_vector_type(4)));
typedef short s16x8 __attribute__((ext_vector_type(8)));

#define LSEQ 2048
#define QIN 512
#define VIN 1024
#define KCAT 704
#define KEFF 2560
#define NORMS 0.10206207261596575f  // 1/sqrt(96)

__device__ __forceinline__ u16 f2bf(float f) {
  u32 u = __float_as_uint(f);
  u = (u + 0x7fffu + ((u >> 16) & 1u)) >> 16;  // RNE
  return (u16)u;
}
__device__ __forceinline__ float bf2f(u16 v) {
  return __uint_as_float(((u32)v) << 16);
}

__device__ __forceinline__ s16x8 load8cvt(const float* __restrict__ p) {
  float4 a = *(const float4*)p;
  float4 b = *(const float4*)(p + 4);
  s16x8 r;
  r[0] = (short)f2bf(a.x); r[1] = (short)f2bf(a.y);
  r[2] = (short)f2bf(a.z); r[3] = (short)f2bf(a.w);
  r[4] = (short)f2bf(b.x); r[5] = (short)f2bf(b.y);
  r[6] = (short)f2bf(b.z); r[7] = (short)f2bf(b.w);
  return r;
}

__device__ __forceinline__ s16x8 cvt2x4(float4 a, float4 b) {
  s16x8 r;
  r[0] = (short)f2bf(a.x); r[1] = (short)f2bf(a.y);
  r[2] = (short)f2bf(a.z); r[3] = (short)f2bf(a.w);
  r[4] = (short)f2bf(b.x); r[5] = (short)f2bf(b.y);
  r[6] = (short)f2bf(b.z); r[7] = (short)f2bf(b.w);
  return r;
}

// Fragment-linear index for a weight matrix W[N=96][K]:
// element W[o][k] -> ((kc*6 + nt)*64 + kg*16 + ln)*8 + j
__device__ __forceinline__ size_t wfrag_idx(int o, int k) {
  int kc = k >> 5, kg = (k >> 3) & 3, j = k & 7;
  int nt = o >> 4, ln = o & 15;
  return ((size_t)(kc * 6 + nt) * 64 + kg * 16 + ln) * 8 + j;
}

// ---------------------------------------------------------------------------
// Kernel 1 (prep1): conv-weight transposes (c3t[t][c][j], c5t[t][c][j]),
// q_w/v_w -> frag bf16, k_w conv-slices -> tiny frags kw3f/kw5f, b_eff.
// ---------------------------------------------------------------------------
__global__ __launch_bounds__(256) void prep1(
    const float* __restrict__ q_w, const float* __restrict__ k_w,
    const float* __restrict__ k_b, const float* __restrict__ v_w,
    const float* __restrict__ cn3_w, const float* __restrict__ cn3_b,
    const float* __restrict__ cn5_w, const float* __restrict__ cn5_b,
    float* __restrict__ c3t, float* __restrict__ c5t,
    u16* __restrict__ qwf, u16* __restrict__ vwf,
    u16* __restrict__ kw3f, u16* __restrict__ kw5f,
    float* __restrict__ beff) {
  int blk = blockIdx.x, tid = threadIdx.x;
  if (blk < 576) {                       // c3t: 147456
    int idx = blk * 256 + tid;
    int t = idx / (512 * 96);
    int rem = idx - t * 512 * 96;
    int c = rem / 96, j = rem - c * 96;
    c3t[idx] = cn3_w[(j * 512 + c) * 3 + t];
  } else if (blk < 1536) {               // c5t: 245760
    int idx = (blk - 576) * 256 + tid;
    int t = idx / (512 * 96);
    int rem = idx - t * 512 * 96;
    int c = rem / 96, j = rem - c * 96;
    c5t[idx] = cn5_w[(j * 512 + c) * 5 + t];
  } else if (blk < 1728) {               // qwf: 49152
    int e = (blk - 1536) * 256 + tid;
    int o = e >> 9, k = e & 511;
    qwf[wfrag_idx(o, k)] = f2bf(q_w[e]);
  } else if (blk < 2112) {               // vwf: 98304
    int e = (blk - 1728) * 256 + tid;
    int o = e >> 10, k = e & 1023;
    vwf[wfrag_idx(o, k)] = f2bf(v_w[e]);
  } else if (blk < 2184) {               // kw3f + kw5f: 2*9216
    int e = (blk - 2112) * 256 + tid;
    int half = e / 9216;
    int i = e - half * 9216;
    int o = i / 96, j = i - o * 96;
    float v = k_w[o * KCAT + (half ? 608 : 512) + j];
    size_t di = ((size_t)((j >> 5) * 6 + (o >> 4)) * 64 +
                 ((j >> 3) & 3) * 16 + (o & 15)) * 8 + (j & 7);
    (half ? kw5f : kw3f)[di] = f2bf(v);
  } else {                               // b_eff
    if (tid < 96) {
      const float* kwo = k_w + tid * KCAT;
      float b = k_b[tid];
      for (int j = 0; j < 96; ++j)
        b += kwo[512 + j] * cn3_b[j] + kwo[608 + j] * cn5_b[j];
      beff[tid] = b;
    }
  }
}

// ---------------------------------------------------------------------------
// Kernel 2 (prep2): W_eff fold as a GEMM (M=2560, N=96, K=96).
// ---------------------------------------------------------------------------
__global__ __launch_bounds__(256) void prep2(
    const float* __restrict__ c3t, const float* __restrict__ c5t,
    const u16* __restrict__ kw3f, const u16* __restrict__ kw5f,
    const float* __restrict__ k_w, u16* __restrict__ wefff) {
  __shared__ float Ls[4][16][100];
  int blk = blockIdx.x, tid = threadIdx.x;
  int wid = tid >> 6, lane = tid & 63, ln = lane & 15, kg = lane >> 4;
  int k = blk * 64 + wid * 16 + ln;
  bool c3ok = (k >= 512) && (k < 2048);
  const float* a5 = c5t + (size_t)k * 96;
  const float* a3 = c3t + (size_t)(c3ok ? k - 512 : 0) * 96;
  f32x4 acc[6];
  #pragma unroll
  for (int nt = 0; nt < 6; ++nt) acc[nt] = (f32x4){0.f, 0.f, 0.f, 0.f};
  #pragma unroll
  for (int jc = 0; jc < 3; ++jc) {
    s16x8 aa5 = load8cvt(a5 + jc * 32 + kg * 8);
    s16x8 aa3 = (s16x8){0, 0, 0, 0, 0, 0, 0, 0};
    if (c3ok) aa3 = load8cvt(a3 + jc * 32 + kg * 8);
    const u16* b5 = kw5f + (size_t)jc * 3072 + lane * 8;
    const u16* b3 = kw3f + (size_t)jc * 3072 + lane * 8;
    #pragma unroll
    for (int nt = 0; nt < 6; ++nt) {
      acc[nt] = __builtin_amdgcn_mfma_f32_16x16x32_bf16(
          aa5, *(const s16x8*)&b5[nt * 512], acc[nt], 0, 0, 0);
      acc[nt] = __builtin_amdgcn_mfma_f32_16x16x32_bf16(
          aa3, *(const s16x8*)&b3[nt * 512], acc[nt], 0, 0, 0);
    }
  }
  #pragma unroll
  for (int nt = 0; nt < 6; ++nt)
    #pragma unroll
    for (int r = 0; r < 4; ++r)
      Ls[wid][kg * 4 + r][nt * 16 + ln] = acc[nt][r];
  asm volatile("s_waitcnt lgkmcnt(0)" ::: "memory");
  #pragma unroll
  for (int sl = 0; sl < 3; ++sl) {
    int slot = sl * 64 + lane;
    int o = slot >> 1, rc = slot & 1;
    int k0 = blk * 64 + wid * 16 + rc * 8;
    int t = k0 >> 9, cbase = k0 & 511;
    s16x8 ov;
    #pragma unroll
    for (int e = 0; e < 8; ++e) {
      float v = Ls[wid][rc * 8 + e][o];
      if (t == 2) v += k_w[o * KCAT + cbase + e];
      ov[e] = (short)f2bf(v);
    }
    *(s16x8*)&wefff[((size_t)((k0 >> 5) * 6 + (o >> 4)) * 64 +
                     ((k0 >> 3) & 3) * 16 + (o & 15)) * 8] = ov;
  }
}

// ---------------------------------------------------------------------------
// Kernel 3: Q+K-conv and V projections fused (round-13 structure).  NEW:
// linear 512-grid with QK = bids [0,256), V = bids [256,512) so co-resident
// pairs (bid, bid+256) are one compute-bound QK + one memory-bound V block
// (heterogeneous pairing -> less pipe contention than QK+QK / V+V).
// ---------------------------------------------------------------------------
__global__ __launch_bounds__(256, 2) void proj_fused(
    const float* __restrict__ evo, const float* __restrict__ plm,
    const u16* __restrict__ qwf, const u16* __restrict__ vwf,
    const u16* __restrict__ wefff, const float* __restrict__ q_b,
    const float* __restrict__ beff, const float* __restrict__ v_b,
    u16* __restrict__ Qf, u16* __restrict__ Kf,
    u16* __restrict__ Vfr, u16* __restrict__ Vb) {
  __shared__ u16 At[2 * 68 * 72];     // 19584 B, A double-buffer
  __shared__ u16 LBS[18432];          // 36864 B, B single-buffer (+ Ls alias)
  float* Ls = (float*)LBS;            // epilogue scratch: [wid*1600 + r*100 + c]
  int bid = blockIdx.x;               // 0..511 linear
  int tid = threadIdx.x;
  int wid = tid >> 6, lane = tid & 63, ln = lane & 15, kg = lane >> 4;
  int srow = tid >> 2, spart = tid & 3;

  if (bid < 256) {
    // ---------------- QK path (A = evo, 68-row halo tile) ----------------
    int bx = bid & 31, bb = bid >> 5;
    int r0 = bx * 64;
    const float* xb = evo + (size_t)bb * LSEQ * QIN;
    bool halo = tid < 16;
    int hrow = 64 + (tid >> 2);

    float4 ra0, ra1, ra2, ra3, rb0, rb1, rb2, rb3;
    auto LOADS = [&](int s) {
      int g = r0 - 2 + srow;
      if (g >= 0 && g < LSEQ) {
        const float* p = xb + (size_t)g * QIN + s * 64 + spart * 16;
        ra0 = *(const float4*)p;       ra1 = *(const float4*)(p + 4);
        ra2 = *(const float4*)(p + 8); ra3 = *(const float4*)(p + 12);
      } else {
        ra0 = ra1 = ra2 = ra3 = make_float4(0.f, 0.f, 0.f, 0.f);
      }
      if (halo) {
        int g2 = r0 - 2 + hrow;
        if (g2 < LSEQ) {
          const float* p = xb + (size_t)g2 * QIN + s * 64 + spart * 16;
          rb0 = *(const float4*)p;       rb1 = *(const float4*)(p + 4);
          rb2 = *(const float4*)(p + 8); rb3 = *(const float4*)(p + 12);
        } else {
          rb0 = rb1 = rb2 = rb3 = make_float4(0.f, 0.f, 0.f, 0.f);
        }
      }
    };
    auto WRITES = [&](int buf) {
      u16* d = &At[(buf * 68 + srow) * 72 + spart * 16];
      *(s16x8*)d = cvt2x4(ra0, ra1);
      *(s16x8*)(d + 8) = cvt2x4(ra2, ra3);
      if (halo) {
        u16* d2 = &At[(buf * 68 + hrow) * 72 + spart * 16];
        *(s16x8*)d2 = cvt2x4(rb0, rb1);
        *(s16x8*)(d2 + 8) = cvt2x4(rb2, rb3);
      }
    };

    // B staging: 36 KB = [Q, tap0..tap4][kcg slice 6KB]; 9x16B per thread
    s16x8 br[9];
    auto LOADB = [&](int kcg) {
      #pragma unroll
      for (int j = 0; j < 9; ++j) {
        int idx = tid + j * 256;
        int chunk = idx / 384;           // 0=Q, 1..5=taps
        int off = idx - chunk * 384;
        const u16* src = (chunk == 0)
            ? qwf + (size_t)kcg * 3072 + off * 8
            : wefff + (size_t)(chunk - 1) * 49152 + (size_t)kcg * 3072 + off * 8;
        br[j] = *(const s16x8*)src;
      }
    };
    auto STOREB = [&]() {
      #pragma unroll
      for (int j = 0; j < 9; ++j) {
        int idx = tid + j * 256;
        *(s16x8*)&LBS[idx * 8] = br[j];
      }
    };

    f32x4 accQ[6], accK[6];
    #pragma unroll
    for (int nt = 0; nt < 6; ++nt) {
      accQ[nt] = (f32x4){0.f, 0.f, 0.f, 0.f};
      accK[nt] = (f32x4){0.f, 0.f, 0.f, 0.f};
    }

    LOADS(0);
    LOADB(0);
    WRITES(0);
    STOREB();
    __syncthreads();
    int cur = 0;
    for (int s = 0; s < 8; ++s) {
      if (s < 7) LOADS(s + 1);
      #pragma unroll
      for (int cc = 0; cc < 2; ++cc) {
        int kcg = s * 2 + cc;
        bool havenext = kcg < 15;
        if (havenext) LOADB(kcg + 1);
        const u16* arow = &At[(cur * 68 + wid * 16 + ln) * 72 + cc * 32 + kg * 8];
        s16x8 aQ  = *(const s16x8*)&arow[2 * 72];
        s16x8 aK0 = *(const s16x8*)&arow[0];
        s16x8 aK1 = *(const s16x8*)&arow[1 * 72];
        s16x8 aK3 = *(const s16x8*)&arow[3 * 72];
        s16x8 aK4 = *(const s16x8*)&arow[4 * 72];
        const u16* lb = LBS + lane * 8;
        s16x8 bfr[6];
        #pragma unroll
        for (int i = 0; i < 6; ++i)
          bfr[i] = *(const s16x8*)&lb[i * 512];
        #pragma unroll
        for (int i = 0; i < 6; ++i)
          accQ[i] = __builtin_amdgcn_mfma_f32_16x16x32_bf16(
              aQ, bfr[i], accQ[i], 0, 0, 0);
        #pragma unroll
        for (int t = 0; t < 5; ++t) {
          s16x8 bf2[6];
          #pragma unroll
          for (int i = 0; i < 6; ++i)
            bf2[i] = *(const s16x8*)&lb[(1 + t) * 3072 + i * 512];
          s16x8 aK = (t == 0) ? aK0 : (t == 1) ? aK1 : (t == 2) ? aQ
                   : (t == 3) ? aK3 : aK4;
          #pragma unroll
          for (int i = 0; i < 6; ++i)
            accK[i] = __builtin_amdgcn_mfma_f32_16x16x32_bf16(
                aK, bf2[i], accK[i], 0, 0, 0);
        }
        __syncthreads();                 // everyone done reading LBS
        if (havenext) STOREB();
        if (cc == 1 && s < 7) WRITES(cur ^ 1);
        __syncthreads();                 // B(next) + A(next) published
      }
      if (s < 7) cur ^= 1;
    }

    size_t qt = (size_t)bb * 128 + bx * 4 + wid;
    #pragma unroll
    for (int nt = 0; nt < 6; ++nt)
      #pragma unroll
      for (int r = 0; r < 4; ++r)
        Ls[wid * 1600 + (kg * 4 + r) * 100 + nt * 16 + ln] = accQ[nt][r];
    asm volatile("s_waitcnt lgkmcnt(0)" ::: "memory");
    #pragma unroll
    for (int sl = 0; sl < 3; ++sl) {
      int slot = sl * 64 + lane;
      int r = slot / 12, cg = slot % 12;
      s16x8 ov;
      #pragma unroll
      for (int e = 0; e < 8; ++e) {
        int c = cg * 8 + e;
        ov[e] = (short)f2bf(Ls[wid * 1600 + r * 100 + c] + q_b[c]);
      }
      *(s16x8*)&Qf[((qt * 3 + (cg >> 2)) * 64 + (cg & 3) * 16 + r) * 8] = ov;
    }
    asm volatile("s_waitcnt lgkmcnt(0) vmcnt(0)" ::: "memory");
    #pragma unroll
    for (int nt = 0; nt < 6; ++nt)
      #pragma unroll
      for (int r = 0; r < 4; ++r)
        Ls[wid * 1600 + (kg * 4 + r) * 100 + nt * 16 + ln] = accK[nt][r];
    asm volatile("s_waitcnt lgkmcnt(0)" ::: "memory");
    #pragma unroll
    for (int sl = 0; sl < 3; ++sl) {
      int slot = sl * 64 + lane;
      int r = slot / 12, cg = slot % 12;
      s16x8 ov;
      #pragma unroll
      for (int e = 0; e < 8; ++e) {
        int c = cg * 8 + e;
        ov[e] = (short)f2bf(Ls[wid * 1600 + r * 100 + c] + beff[c]);
      }
      *(s16x8*)&Kf[((qt * 3 + (cg >> 2)) * 64 + (cg & 3) * 16 + r) * 8] = ov;
    }
  } else {
    // ---------------- V path (A = plm, 64-row tile, K=1024) ----------------
    int i = bid - 256;
    int bx = i & 31, bb = i >> 5;
    const float* xb = plm + ((size_t)bb * LSEQ + bx * 64) * VIN;
    float4 ra0, ra1, ra2, ra3;
    auto LOADS = [&](int s) {
      const float* p = xb + (size_t)srow * VIN + s * 64 + spart * 16;
      ra0 = *(const float4*)p;       ra1 = *(const float4*)(p + 4);
      ra2 = *(const float4*)(p + 8); ra3 = *(const float4*)(p + 12);
    };
    auto WRITES = [&](int buf) {
      u16* d = &At[(buf * 68 + srow) * 72 + spart * 16];
      *(s16x8*)d = cvt2x4(ra0, ra1);
      *(s16x8*)(d + 8) = cvt2x4(ra2, ra3);
    };
    // B staging: 12 KB per s-step (2 kcg, contiguous in vwf); 3x16B/thread
    s16x8 br[3];
    auto LOADB = [&](int s) {
      #pragma unroll
      for (int j = 0; j < 3; ++j) {
        int idx = tid + j * 256;
        br[j] = *(const s16x8*)(vwf + (size_t)s * 6144 + idx * 8);
      }
    };
    auto STOREB = [&]() {
      #pragma unroll
      for (int j = 0; j < 3; ++j) {
        int idx = tid + j * 256;
        *(s16x8*)&LBS[idx * 8] = br[j];
      }
    };

    f32x4 acc[6];
    #pragma unroll
    for (int nt = 0; nt < 6; ++nt) acc[nt] = (f32x4){0.f, 0.f, 0.f, 0.f};

    LOADS(0);
    LOADB(0);
    WRITES(0);
    STOREB();
    __syncthreads();
    int cur = 0;
    for (int s = 0; s < 16; ++s) {
      if (s < 15) {
        LOADS(s + 1);
        LOADB(s + 1);
      }
      #pragma unroll
      for (int cc = 0; cc < 2; ++cc) {
        s16x8 a = *(const s16x8*)&At[(cur * 68 + wid * 16 + ln) * 72 +
                                     cc * 32 + kg * 8];
        const u16* lb = LBS + cc * 3072 + lane * 8;
        s16x8 bfr[6];
        #pragma unroll
        for (int nt = 0; nt < 6; ++nt)
          bfr[nt] = *(const s16x8*)&lb[nt * 512];
        #pragma unroll
        for (int nt = 0; nt < 6; ++nt)
          acc[nt] = __builtin_amdgcn_mfma_f32_16x16x32_bf16(
              a, bfr[nt], acc[nt], 0, 0, 0);
      }
      __syncthreads();                   // done reading LBS + At[cur]
      if (s < 15) {
        STOREB();
        WRITES(cur ^ 1);
      }
      __syncthreads();                   // B(s+1) + A(s+1) published
      if (s < 15) cur ^= 1;
    }

    #pragma unroll
    for (int nt = 0; nt < 6; ++nt)
      #pragma unroll
      for (int r = 0; r < 4; ++r)
        Ls[wid * 1600 + (kg * 4 + r) * 100 + nt * 16 + ln] = acc[nt][r];
    asm volatile("s_waitcnt lgkmcnt(0)" ::: "memory");
    #pragma unroll
    for (int sl = 0; sl < 3; ++sl) {
      int slot = sl * 64 + lane;
      int r = slot / 12, cg = slot % 12;
      s16x8 ov;
      #pragma unroll
      for (int e = 0; e < 8; ++e) {
        int c = cg * 8 + e;
        ov[e] = (short)f2bf(Ls[wid * 1600 + r * 100 + c] + v_b[c]);
      }
      *(s16x8*)&Vb[((size_t)bb * LSEQ + bx * 64 + wid * 16 + r) * 96 + cg * 8] = ov;
    }
    #pragma unroll
    for (int sl = 0; sl < 3; ++sl) {
      int slot = sl * 64 + lane;
      int c = slot >> 1, rc = slot & 1;
      int key0 = bx * 64 + wid * 16 + rc * 8;
      s16x8 fv;
      #pragma unroll
      for (int e = 0; e < 8; ++e)
        fv[e] = (short)f2bf(Ls[wid * 1600 + (rc * 8 + e) * 100 + c] + v_b[c]);
      *(s16x8*)&Vfr[(((size_t)bb * 64 + (key0 >> 5)) * 6 + (c >> 4)) * 512 +
                    (((key0 >> 3) & 3) * 16 + (c & 15)) * 8] = fv;
    }
  }
}

// ---------------------------------------------------------------------------
// Kernel 4: flash attention + "+V".  Batch-interleaved bid mapping + K-frag
// register prefetch + T5 setprio around MFMA clusters.
// ---------------------------------------------------------------------------
__global__ __launch_bounds__(256, 4) void attn_kernel(
    const u16* __restrict__ Qf, const u16* __restrict__ Kf,
    const u16* __restrict__ Vfr, const u16* __restrict__ Vb,
    const int* __restrict__ seqlen, float* __restrict__ out) {
  __shared__ u16 Ps[4][16][40];
  __shared__ float Cacc[4][16][97];
  __shared__ float Cml[4][16][2];

  int bid = blockIdx.x;
  int bb = (bid >> 3) & 7;
  int bx = ((bid >> 6) << 3) | (bid & 7);
  int tid = threadIdx.x;
  int wid = tid >> 6, lane = tid & 63, ln = lane & 15, kg = lane >> 4;
  int n = seqlen[bb];
  int nkc = (n + 31) >> 5;

  size_t qt = (size_t)bb * 128 + bx;
  s16x8 aQ[3];
  #pragma unroll
  for (int kk = 0; kk < 3; ++kk)
    aQ[kk] = *(const s16x8*)&Qf[((qt * 3 + kk) * 64 + lane) * 8];

  float m[4], lsum[4];
  f32x4 acc[6];
  #pragma unroll
  for (int r = 0; r < 4; ++r) { m[r] = -1e30f; lsum[r] = 0.f; }
  #pragma unroll
  for (int nt = 0; nt < 6; ++nt) acc[nt] = (f32x4){0.f, 0.f, 0.f, 0.f};

  const u16* Kbb = Kf + (size_t)bb * 128 * 1536;
  s16x8 kf[6];
  {
    int k0 = (wid < nkc) ? wid : 0;
    const u16* kp = Kbb + (size_t)k0 * 3072 + lane * 8;
    #pragma unroll
    for (int i = 0; i < 6; ++i) kf[i] = *(const s16x8*)&kp[i * 512];
  }

  for (int kc = wid; kc < nkc; kc += 4) {
    int key0 = kc * 32;
    f32x4 s0 = (f32x4){0.f, 0.f, 0.f, 0.f};
    f32x4 s1 = (f32x4){0.f, 0.f, 0.f, 0.f};
    __builtin_amdgcn_s_setprio(1);
    #pragma unroll
    for (int kk = 0; kk < 3; ++kk) {
      s0 = __builtin_amdgcn_mfma_f32_16x16x32_bf16(aQ[kk], kf[kk], s0, 0, 0, 0);
      s1 = __builtin_amdgcn_mfma_f32_16x16x32_bf16(aQ[kk], kf[3 + kk], s1, 0, 0, 0);
    }
    __builtin_amdgcn_s_setprio(0);

    s16x8 kf2[6];
    {
      int kn = (kc + 4 < nkc) ? kc + 4 : 0;
      const u16* kp = Kbb + (size_t)kn * 3072 + lane * 8;
      #pragma unroll
      for (int i = 0; i < 6; ++i) kf2[i] = *(const s16x8*)&kp[i * 512];
    }

    bool v0 = (key0 + ln) < n;
    bool v1 = (key0 + 16 + ln) < n;
    float sv0[4], sv1[4], mx[4];
    #pragma unroll
    for (int r = 0; r < 4; ++r) {
      sv0[r] = v0 ? s0[r] * NORMS : -1e30f;
      sv1[r] = v1 ? s1[r] * NORMS : -1e30f;
      mx[r] = fmaxf(sv0[r], sv1[r]);
    }
    #pragma unroll
    for (int r = 0; r < 4; ++r) {
      mx[r] = fmaxf(mx[r], __shfl_xor(mx[r], 1, 16));
      mx[r] = fmaxf(mx[r], __shfl_xor(mx[r], 2, 16));
      mx[r] = fmaxf(mx[r], __shfl_xor(mx[r], 4, 16));
      mx[r] = fmaxf(mx[r], __shfl_xor(mx[r], 8, 16));
    }
    float p0[4], p1[4], rs[4];
    bool defer = __all((mx[0] <= m[0] + 8.f) && (mx[1] <= m[1] + 8.f) &&
                       (mx[2] <= m[2] + 8.f) && (mx[3] <= m[3] + 8.f));
    if (defer) {
      #pragma unroll
      for (int r = 0; r < 4; ++r) {
        p0[r] = __expf(sv0[r] - m[r]);
        p1[r] = __expf(sv1[r] - m[r]);
        rs[r] = p0[r] + p1[r];
      }
      #pragma unroll
      for (int r = 0; r < 4; ++r) {
        rs[r] += __shfl_xor(rs[r], 1, 16);
        rs[r] += __shfl_xor(rs[r], 2, 16);
        rs[r] += __shfl_xor(rs[r], 4, 16);
        rs[r] += __shfl_xor(rs[r], 8, 16);
        lsum[r] += rs[r];
      }
    } else {
      float fac[4];
      #pragma unroll
      for (int r = 0; r < 4; ++r) {
        float mn = fmaxf(m[r], mx[r]);
        fac[r] = __expf(m[r] - mn);
        p0[r] = __expf(sv0[r] - mn);
        p1[r] = __expf(sv1[r] - mn);
        rs[r] = p0[r] + p1[r];
        m[r] = mn;
      }
      #pragma unroll
      for (int r = 0; r < 4; ++r) {
        rs[r] += __shfl_xor(rs[r], 1, 16);
        rs[r] += __shfl_xor(rs[r], 2, 16);
        rs[r] += __shfl_xor(rs[r], 4, 16);
        rs[r] += __shfl_xor(rs[r], 8, 16);
        lsum[r] = lsum[r] * fac[r] + rs[r];
      }
      #pragma unroll
      for (int nt = 0; nt < 6; ++nt)
        #pragma unroll
        for (int r = 0; r < 4; ++r) acc[nt][r] *= fac[r];
    }

    u16* Pw = &Ps[wid][0][0];
    #pragma unroll
    for (int r = 0; r < 4; ++r) {
      Pw[(kg * 4 + r) * 40 + ln] = f2bf(p0[r]);
      Pw[(kg * 4 + r) * 40 + 16 + ln] = f2bf(p1[r]);
    }
    s16x8 pa = *(const s16x8*)&Pw[ln * 40 + kg * 8];

    const u16* vf = Vfr + (((size_t)bb * 64 + kc) * 6 * 64) * 8 + lane * 8;
    s16x8 bv[6];
    #pragma unroll
    for (int nt = 0; nt < 6; ++nt)
      bv[nt] = *(const s16x8*)&vf[(size_t)nt * 512];
    __builtin_amdgcn_s_setprio(1);
    #pragma unroll
    for (int nt = 0; nt < 6; ++nt)
      acc[nt] = __builtin_amdgcn_mfma_f32_16x16x32_bf16(pa, bv[nt], acc[nt], 0, 0, 0);
    __builtin_amdgcn_s_setprio(0);
    #pragma unroll
    for (int i = 0; i < 6; ++i) kf[i] = kf2[i];
  }

  #pragma unroll
  for (int nt = 0; nt < 6; ++nt)
    #pragma unroll
    for (int r = 0; r < 4; ++r)
      Cacc[wid][kg * 4 + r][nt * 16 + ln] = acc[nt][r];
  if (ln == 0) {
    #pragma unroll
    for (int r = 0; r < 4; ++r) {
      Cml[wid][kg * 4 + r][0] = m[r];
      Cml[wid][kg * 4 + r][1] = lsum[r];
    }
  }
  __syncthreads();

  size_t obase = ((size_t)bb * LSEQ + bx * 16) * 96;
  for (int i = tid; i < 1536; i += 256) {
    int row = i / 96;
    float mg = -1e30f;
    #pragma unroll
    for (int w = 0; w < 4; ++w) mg = fmaxf(mg, Cml[w][row][0]);
    float lg = 0.f, av = 0.f;
    #pragma unroll
    for (int w = 0; w < 4; ++w) {
      float e = __expf(Cml[w][row][0] - mg);
      lg += Cml[w][row][1] * e;
      av += Cacc[w][row][i - row * 96] * e;
    }
    out[obase + i] = av / lg + bf2f(Vb[obase + i]);
  }
}

// ---------------------------------------------------------------------------
extern "C" void kernel_launch(void* const* d_in, const int* in_sizes, int n_in,
                              void* d_out, int out_size, void* d_ws,
                              size_t ws_size, hipStream_t stream) {
  const float* plm   = (const float*)d_in[0];
  const float* evo   = (const float*)d_in[1];
  const int* seqlen  = (const int*)d_in[2];
  const float* q_w   = (const float*)d_in[3];
  const float* q_b   = (const float*)d_in[4];
  const float* k_w   = (const float*)d_in[5];
  const float* k_b   = (const float*)d_in[6];
  const float* v_w   = (const float*)d_in[7];
  const float* v_b   = (const float*)d_in[8];
  const float* cn3_w = (const float*)d_in[9];
  const float* cn3_b = (const float*)d_in[10];
  const float* cn5_w = (const float*)d_in[11];
  const float* cn5_b = (const float*)d_in[12];

  char* ws = (char*)d_ws;
  u16* wefff  = (u16*)(ws + 0);           // 491520
  float* beff = (float*)(ws + 491520);    // 512
  u16* qwf    = (u16*)(ws + 492032);      // 98304
  u16* vwf    = (u16*)(ws + 590336);      // 196608
  float* c3t  = (float*)(ws + 786944);    // 589824
  float* c5t  = (float*)(ws + 1376768);   // 983040
  u16* kw3f   = (u16*)(ws + 2359808);     // 18432
  u16* kw5f   = (u16*)(ws + 2378240);     // 18432
  u16* Qf     = (u16*)(ws + 2396672);     // 3145728
  u16* Kf     = (u16*)(ws + 5542400);     // 3145728
  u16* Vfr    = (u16*)(ws + 8688128);     // 3145728
  u16* Vb     = (u16*)(ws + 11833856);    // 3145728
  float* out  = (float*)d_out;

  prep1<<<2185, 256, 0, stream>>>(q_w, k_w, k_b, v_w, cn3_w, cn3_b, cn5_w,
                                  cn5_b, c3t, c5t, qwf, vwf, kw3f, kw5f, beff);
  prep2<<<40, 256, 0, stream>>>(c3t, c5t, kw3f, kw5f, k_w, wefff);
  proj_fused<<<512, 256, 0, stream>>>(evo, plm, qwf, vwf, wefff,
                                      q_b, beff, v_b, Qf, Kf, Vfr, Vb);
  attn_kernel<<<1024, 256, 0, stream>>>(Qf, Kf, Vfr, Vb, seqlen, out);
}

// Round 18
// 81.980 us; speedup vs baseline: 1.9466x; 1.0096x over previous
//
#include <hip/hip_runtime.h>

typedef unsigned short u16;
typedef unsigned int u32;
typedef float f32x4 __attribute__((ext_vector_type(4)));
typedef short s16x8 __attribute__((ext_vector_type(8)));

#define LSEQ 2048
#define QIN 512
#define VIN 1024
#define KCAT 704
#define KEFF 2560
#define NORMS 0.10206207261596575f  // 1/sqrt(96)

__device__ __forceinline__ u16 f2bf(float f) {
  u32 u = __float_as_uint(f);
  u = (u + 0x7fffu + ((u >> 16) & 1u)) >> 16;  // RNE
  return (u16)u;
}
__device__ __forceinline__ float bf2f(u16 v) {
  return __uint_as_float(((u32)v) << 16);
}

__device__ __forceinline__ s16x8 load8cvt(const float* __restrict__ p) {
  float4 a = *(const float4*)p;
  float4 b = *(const float4*)(p + 4);
  s16x8 r;
  r[0] = (short)f2bf(a.x); r[1] = (short)f2bf(a.y);
  r[2] = (short)f2bf(a.z); r[3] = (short)f2bf(a.w);
  r[4] = (short)f2bf(b.x); r[5] = (short)f2bf(b.y);
  r[6] = (short)f2bf(b.z); r[7] = (short)f2bf(b.w);
  return r;
}

__device__ __forceinline__ s16x8 cvt2x4(float4 a, float4 b) {
  s16x8 r;
  r[0] = (short)f2bf(a.x); r[1] = (short)f2bf(a.y);
  r[2] = (short)f2bf(a.z); r[3] = (short)f2bf(a.w);
  r[4] = (short)f2bf(b.x); r[5] = (short)f2bf(b.y);
  r[6] = (short)f2bf(b.z); r[7] = (short)f2bf(b.w);
  return r;
}

// Fragment-linear index for a weight matrix W[N=96][K]:
// element W[o][k] -> ((kc*6 + nt)*64 + kg*16 + ln)*8 + j
__device__ __forceinline__ size_t wfrag_idx(int o, int k) {
  int kc = k >> 5, kg = (k >> 3) & 3, j = k & 7;
  int nt = o >> 4, ln = o & 15;
  return ((size_t)(kc * 6 + nt) * 64 + kg * 16 + ln) * 8 + j;
}

// ---------------------------------------------------------------------------
// Kernel 1 (prep1): conv-weight transposes (c3t[t][c][j], c5t[t][c][j]),
// q_w/v_w -> frag bf16, k_w conv-slices -> tiny frags kw3f/kw5f, b_eff.
// ---------------------------------------------------------------------------
__global__ __launch_bounds__(256) void prep1(
    const float* __restrict__ q_w, const float* __restrict__ k_w,
    const float* __restrict__ k_b, const float* __restrict__ v_w,
    const float* __restrict__ cn3_w, const float* __restrict__ cn3_b,
    const float* __restrict__ cn5_w, const float* __restrict__ cn5_b,
    float* __restrict__ c3t, float* __restrict__ c5t,
    u16* __restrict__ qwf, u16* __restrict__ vwf,
    u16* __restrict__ kw3f, u16* __restrict__ kw5f,
    float* __restrict__ beff) {
  int blk = blockIdx.x, tid = threadIdx.x;
  if (blk < 576) {                       // c3t: 147456
    int idx = blk * 256 + tid;
    int t = idx / (512 * 96);
    int rem = idx - t * 512 * 96;
    int c = rem / 96, j = rem - c * 96;
    c3t[idx] = cn3_w[(j * 512 + c) * 3 + t];
  } else if (blk < 1536) {               // c5t: 245760
    int idx = (blk - 576) * 256 + tid;
    int t = idx / (512 * 96);
    int rem = idx - t * 512 * 96;
    int c = rem / 96, j = rem - c * 96;
    c5t[idx] = cn5_w[(j * 512 + c) * 5 + t];
  } else if (blk < 1728) {               // qwf: 49152
    int e = (blk - 1536) * 256 + tid;
    int o = e >> 9, k = e & 511;
    qwf[wfrag_idx(o, k)] = f2bf(q_w[e]);
  } else if (blk < 2112) {               // vwf: 98304
    int e = (blk - 1728) * 256 + tid;
    int o = e >> 10, k = e & 1023;
    vwf[wfrag_idx(o, k)] = f2bf(v_w[e]);
  } else if (blk < 2184) {               // kw3f + kw5f: 2*9216
    int e = (blk - 2112) * 256 + tid;
    int half = e / 9216;
    int i = e - half * 9216;
    int o = i / 96, j = i - o * 96;
    float v = k_w[o * KCAT + (half ? 608 : 512) + j];
    size_t di = ((size_t)((j >> 5) * 6 + (o >> 4)) * 64 +
                 ((j >> 3) & 3) * 16 + (o & 15)) * 8 + (j & 7);
    (half ? kw5f : kw3f)[di] = f2bf(v);
  } else {                               // b_eff
    if (tid < 96) {
      const float* kwo = k_w + tid * KCAT;
      float b = k_b[tid];
      for (int j = 0; j < 96; ++j)
        b += kwo[512 + j] * cn3_b[j] + kwo[608 + j] * cn5_b[j];
      beff[tid] = b;
    }
  }
}

// ---------------------------------------------------------------------------
// Kernel 2 (prep2): W_eff fold as a GEMM (M=2560, N=96, K=96).
// ---------------------------------------------------------------------------
__global__ __launch_bounds__(256) void prep2(
    const float* __restrict__ c3t, const float* __restrict__ c5t,
    const u16* __restrict__ kw3f, const u16* __restrict__ kw5f,
    const float* __restrict__ k_w, u16* __restrict__ wefff) {
  __shared__ float Ls[4][16][100];
  int blk = blockIdx.x, tid = threadIdx.x;
  int wid = tid >> 6, lane = tid & 63, ln = lane & 15, kg = lane >> 4;
  int k = blk * 64 + wid * 16 + ln;
  bool c3ok = (k >= 512) && (k < 2048);
  const float* a5 = c5t + (size_t)k * 96;
  const float* a3 = c3t + (size_t)(c3ok ? k - 512 : 0) * 96;
  f32x4 acc[6];
  #pragma unroll
  for (int nt = 0; nt < 6; ++nt) acc[nt] = (f32x4){0.f, 0.f, 0.f, 0.f};
  #pragma unroll
  for (int jc = 0; jc < 3; ++jc) {
    s16x8 aa5 = load8cvt(a5 + jc * 32 + kg * 8);
    s16x8 aa3 = (s16x8){0, 0, 0, 0, 0, 0, 0, 0};
    if (c3ok) aa3 = load8cvt(a3 + jc * 32 + kg * 8);
    const u16* b5 = kw5f + (size_t)jc * 3072 + lane * 8;
    const u16* b3 = kw3f + (size_t)jc * 3072 + lane * 8;
    #pragma unroll
    for (int nt = 0; nt < 6; ++nt) {
      acc[nt] = __builtin_amdgcn_mfma_f32_16x16x32_bf16(
          aa5, *(const s16x8*)&b5[nt * 512], acc[nt], 0, 0, 0);
      acc[nt] = __builtin_amdgcn_mfma_f32_16x16x32_bf16(
          aa3, *(const s16x8*)&b3[nt * 512], acc[nt], 0, 0, 0);
    }
  }
  #pragma unroll
  for (int nt = 0; nt < 6; ++nt)
    #pragma unroll
    for (int r = 0; r < 4; ++r)
      Ls[wid][kg * 4 + r][nt * 16 + ln] = acc[nt][r];
  asm volatile("s_waitcnt lgkmcnt(0)" ::: "memory");
  #pragma unroll
  for (int sl = 0; sl < 3; ++sl) {
    int slot = sl * 64 + lane;
    int o = slot >> 1, rc = slot & 1;
    int k0 = blk * 64 + wid * 16 + rc * 8;
    int t = k0 >> 9, cbase = k0 & 511;
    s16x8 ov;
    #pragma unroll
    for (int e = 0; e < 8; ++e) {
      float v = Ls[wid][rc * 8 + e][o];
      if (t == 2) v += k_w[o * KCAT + cbase + e];
      ov[e] = (short)f2bf(v);
    }
    *(s16x8*)&wefff[((size_t)((k0 >> 5) * 6 + (o >> 4)) * 64 +
                     ((k0 >> 3) & 3) * 16 + (o & 15)) * 8] = ov;
  }
}

// ---------------------------------------------------------------------------
// Kernel 3: Q+K-conv and V projections fused (round-17 structure).  Linear
// 512-grid: QK = bids [0,256), V = bids [256,512) so co-resident pairs
// (bid, bid+256) are one compute-bound QK + one memory-bound V block.
// ---------------------------------------------------------------------------
__global__ __launch_bounds__(256, 2) void proj_fused(
    const float* __restrict__ evo, const float* __restrict__ plm,
    const u16* __restrict__ qwf, const u16* __restrict__ vwf,
    const u16* __restrict__ wefff, const float* __restrict__ q_b,
    const float* __restrict__ beff, const float* __restrict__ v_b,
    u16* __restrict__ Qf, u16* __restrict__ Kf,
    u16* __restrict__ Vfr, u16* __restrict__ Vb) {
  __shared__ u16 At[2 * 68 * 72];     // 19584 B, A double-buffer
  __shared__ u16 LBS[18432];          // 36864 B, B single-buffer (+ Ls alias)
  float* Ls = (float*)LBS;            // epilogue scratch: [wid*1600 + r*100 + c]
  int bid = blockIdx.x;               // 0..511 linear
  int tid = threadIdx.x;
  int wid = tid >> 6, lane = tid & 63, ln = lane & 15, kg = lane >> 4;
  int srow = tid >> 2, spart = tid & 3;

  if (bid < 256) {
    // ---------------- QK path (A = evo, 68-row halo tile) ----------------
    int bx = bid & 31, bb = bid >> 5;
    int r0 = bx * 64;
    const float* xb = evo + (size_t)bb * LSEQ * QIN;
    bool halo = tid < 16;
    int hrow = 64 + (tid >> 2);

    float4 ra0, ra1, ra2, ra3, rb0, rb1, rb2, rb3;
    auto LOADS = [&](int s) {
      int g = r0 - 2 + srow;
      if (g >= 0 && g < LSEQ) {
        const float* p = xb + (size_t)g * QIN + s * 64 + spart * 16;
        ra0 = *(const float4*)p;       ra1 = *(const float4*)(p + 4);
        ra2 = *(const float4*)(p + 8); ra3 = *(const float4*)(p + 12);
      } else {
        ra0 = ra1 = ra2 = ra3 = make_float4(0.f, 0.f, 0.f, 0.f);
      }
      if (halo) {
        int g2 = r0 - 2 + hrow;
        if (g2 < LSEQ) {
          const float* p = xb + (size_t)g2 * QIN + s * 64 + spart * 16;
          rb0 = *(const float4*)p;       rb1 = *(const float4*)(p + 4);
          rb2 = *(const float4*)(p + 8); rb3 = *(const float4*)(p + 12);
        } else {
          rb0 = rb1 = rb2 = rb3 = make_float4(0.f, 0.f, 0.f, 0.f);
        }
      }
    };
    auto WRITES = [&](int buf) {
      u16* d = &At[(buf * 68 + srow) * 72 + spart * 16];
      *(s16x8*)d = cvt2x4(ra0, ra1);
      *(s16x8*)(d + 8) = cvt2x4(ra2, ra3);
      if (halo) {
        u16* d2 = &At[(buf * 68 + hrow) * 72 + spart * 16];
        *(s16x8*)d2 = cvt2x4(rb0, rb1);
        *(s16x8*)(d2 + 8) = cvt2x4(rb2, rb3);
      }
    };

    // B staging: 36 KB = [Q, tap0..tap4][kcg slice 6KB]; 9x16B per thread
    s16x8 br[9];
    auto LOADB = [&](int kcg) {
      #pragma unroll
      for (int j = 0; j < 9; ++j) {
        int idx = tid + j * 256;
        int chunk = idx / 384;           // 0=Q, 1..5=taps
        int off = idx - chunk * 384;
        const u16* src = (chunk == 0)
            ? qwf + (size_t)kcg * 3072 + off * 8
            : wefff + (size_t)(chunk - 1) * 49152 + (size_t)kcg * 3072 + off * 8;
        br[j] = *(const s16x8*)src;
      }
    };
    auto STOREB = [&]() {
      #pragma unroll
      for (int j = 0; j < 9; ++j) {
        int idx = tid + j * 256;
        *(s16x8*)&LBS[idx * 8] = br[j];
      }
    };

    f32x4 accQ[6], accK[6];
    #pragma unroll
    for (int nt = 0; nt < 6; ++nt) {
      accQ[nt] = (f32x4){0.f, 0.f, 0.f, 0.f};
      accK[nt] = (f32x4){0.f, 0.f, 0.f, 0.f};
    }

    LOADS(0);
    LOADB(0);
    WRITES(0);
    STOREB();
    __syncthreads();
    int cur = 0;
    for (int s = 0; s < 8; ++s) {
      if (s < 7) LOADS(s + 1);
      #pragma unroll
      for (int cc = 0; cc < 2; ++cc) {
        int kcg = s * 2 + cc;
        bool havenext = kcg < 15;
        if (havenext) LOADB(kcg + 1);
        const u16* arow = &At[(cur * 68 + wid * 16 + ln) * 72 + cc * 32 + kg * 8];
        s16x8 aQ  = *(const s16x8*)&arow[2 * 72];
        s16x8 aK0 = *(const s16x8*)&arow[0];
        s16x8 aK1 = *(const s16x8*)&arow[1 * 72];
        s16x8 aK3 = *(const s16x8*)&arow[3 * 72];
        s16x8 aK4 = *(const s16x8*)&arow[4 * 72];
        const u16* lb = LBS + lane * 8;
        s16x8 bfr[6];
        #pragma unroll
        for (int i = 0; i < 6; ++i)
          bfr[i] = *(const s16x8*)&lb[i * 512];
        #pragma unroll
        for (int i = 0; i < 6; ++i)
          accQ[i] = __builtin_amdgcn_mfma_f32_16x16x32_bf16(
              aQ, bfr[i], accQ[i], 0, 0, 0);
        #pragma unroll
        for (int t = 0; t < 5; ++t) {
          s16x8 bf2[6];
          #pragma unroll
          for (int i = 0; i < 6; ++i)
            bf2[i] = *(const s16x8*)&lb[(1 + t) * 3072 + i * 512];
          s16x8 aK = (t == 0) ? aK0 : (t == 1) ? aK1 : (t == 2) ? aQ
                   : (t == 3) ? aK3 : aK4;
          #pragma unroll
          for (int i = 0; i < 6; ++i)
            accK[i] = __builtin_amdgcn_mfma_f32_16x16x32_bf16(
                aK, bf2[i], accK[i], 0, 0, 0);
        }
        __syncthreads();                 // everyone done reading LBS
        if (havenext) STOREB();
        if (cc == 1 && s < 7) WRITES(cur ^ 1);
        __syncthreads();                 // B(next) + A(next) published
      }
      if (s < 7) cur ^= 1;
    }

    size_t qt = (size_t)bb * 128 + bx * 4 + wid;
    #pragma unroll
    for (int nt = 0; nt < 6; ++nt)
      #pragma unroll
      for (int r = 0; r < 4; ++r)
        Ls[wid * 1600 + (kg * 4 + r) * 100 + nt * 16 + ln] = accQ[nt][r];
    asm volatile("s_waitcnt lgkmcnt(0)" ::: "memory");
    #pragma unroll
    for (int sl = 0; sl < 3; ++sl) {
      int slot = sl * 64 + lane;
      int r = slot / 12, cg = slot % 12;
      s16x8 ov;
      #pragma unroll
      for (int e = 0; e < 8; ++e) {
        int c = cg * 8 + e;
        ov[e] = (short)f2bf(Ls[wid * 1600 + r * 100 + c] + q_b[c]);
      }
      *(s16x8*)&Qf[((qt * 3 + (cg >> 2)) * 64 + (cg & 3) * 16 + r) * 8] = ov;
    }
    asm volatile("s_waitcnt lgkmcnt(0) vmcnt(0)" ::: "memory");
    #pragma unroll
    for (int nt = 0; nt < 6; ++nt)
      #pragma unroll
      for (int r = 0; r < 4; ++r)
        Ls[wid * 1600 + (kg * 4 + r) * 100 + nt * 16 + ln] = accK[nt][r];
    asm volatile("s_waitcnt lgkmcnt(0)" ::: "memory");
    #pragma unroll
    for (int sl = 0; sl < 3; ++sl) {
      int slot = sl * 64 + lane;
      int r = slot / 12, cg = slot % 12;
      s16x8 ov;
      #pragma unroll
      for (int e = 0; e < 8; ++e) {
        int c = cg * 8 + e;
        ov[e] = (short)f2bf(Ls[wid * 1600 + r * 100 + c] + beff[c]);
      }
      *(s16x8*)&Kf[((qt * 3 + (cg >> 2)) * 64 + (cg & 3) * 16 + r) * 8] = ov;
    }
  } else {
    // ---------------- V path (A = plm, 64-row tile, K=1024) ----------------
    int i = bid - 256;
    int bx = i & 31, bb = i >> 5;
    const float* xb = plm + ((size_t)bb * LSEQ + bx * 64) * VIN;
    float4 ra0, ra1, ra2, ra3;
    auto LOADS = [&](int s) {
      const float* p = xb + (size_t)srow * VIN + s * 64 + spart * 16;
      ra0 = *(const float4*)p;       ra1 = *(const float4*)(p + 4);
      ra2 = *(const float4*)(p + 8); ra3 = *(const float4*)(p + 12);
    };
    auto WRITES = [&](int buf) {
      u16* d = &At[(buf * 68 + srow) * 72 + spart * 16];
      *(s16x8*)d = cvt2x4(ra0, ra1);
      *(s16x8*)(d + 8) = cvt2x4(ra2, ra3);
    };
    // B staging: 12 KB per s-step (2 kcg, contiguous in vwf); 3x16B/thread
    s16x8 br[3];
    auto LOADB = [&](int s) {
      #pragma unroll
      for (int j = 0; j < 3; ++j) {
        int idx = tid + j * 256;
        br[j] = *(const s16x8*)(vwf + (size_t)s * 6144 + idx * 8);
      }
    };
    auto STOREB = [&]() {
      #pragma unroll
      for (int j = 0; j < 3; ++j) {
        int idx = tid + j * 256;
        *(s16x8*)&LBS[idx * 8] = br[j];
      }
    };

    f32x4 acc[6];
    #pragma unroll
    for (int nt = 0; nt < 6; ++nt) acc[nt] = (f32x4){0.f, 0.f, 0.f, 0.f};

    LOADS(0);
    LOADB(0);
    WRITES(0);
    STOREB();
    __syncthreads();
    int cur = 0;
    for (int s = 0; s < 16; ++s) {
      if (s < 15) {
        LOADS(s + 1);
        LOADB(s + 1);
      }
      #pragma unroll
      for (int cc = 0; cc < 2; ++cc) {
        s16x8 a = *(const s16x8*)&At[(cur * 68 + wid * 16 + ln) * 72 +
                                     cc * 32 + kg * 8];
        const u16* lb = LBS + cc * 3072 + lane * 8;
        s16x8 bfr[6];
        #pragma unroll
        for (int nt = 0; nt < 6; ++nt)
          bfr[nt] = *(const s16x8*)&lb[nt * 512];
        #pragma unroll
        for (int nt = 0; nt < 6; ++nt)
          acc[nt] = __builtin_amdgcn_mfma_f32_16x16x32_bf16(
              a, bfr[nt], acc[nt], 0, 0, 0);
      }
      __syncthreads();                   // done reading LBS + At[cur]
      if (s < 15) {
        STOREB();
        WRITES(cur ^ 1);
      }
      __syncthreads();                   // B(s+1) + A(s+1) published
      if (s < 15) cur ^= 1;
    }

    #pragma unroll
    for (int nt = 0; nt < 6; ++nt)
      #pragma unroll
      for (int r = 0; r < 4; ++r)
        Ls[wid * 1600 + (kg * 4 + r) * 100 + nt * 16 + ln] = acc[nt][r];
    asm volatile("s_waitcnt lgkmcnt(0)" ::: "memory");
    #pragma unroll
    for (int sl = 0; sl < 3; ++sl) {
      int slot = sl * 64 + lane;
      int r = slot / 12, cg = slot % 12;
      s16x8 ov;
      #pragma unroll
      for (int e = 0; e < 8; ++e) {
        int c = cg * 8 + e;
        ov[e] = (short)f2bf(Ls[wid * 1600 + r * 100 + c] + v_b[c]);
      }
      *(s16x8*)&Vb[((size_t)bb * LSEQ + bx * 64 + wid * 16 + r) * 96 + cg * 8] = ov;
    }
    #pragma unroll
    for (int sl = 0; sl < 3; ++sl) {
      int slot = sl * 64 + lane;
      int c = slot >> 1, rc = slot & 1;
      int key0 = bx * 64 + wid * 16 + rc * 8;
      s16x8 fv;
      #pragma unroll
      for (int e = 0; e < 8; ++e)
        fv[e] = (short)f2bf(Ls[wid * 1600 + (rc * 8 + e) * 100 + c] + v_b[c]);
      *(s16x8*)&Vfr[(((size_t)bb * 64 + (key0 >> 5)) * 6 + (c >> 4)) * 512 +
                    (((key0 >> 3) & 3) * 16 + (c & 15)) * 8] = fv;
    }
  }
}

// ---------------------------------------------------------------------------
// Kernel 4: flash attention + "+V".  NEW mapping: each XCD (bid&7) hosts 4
// batches (working set 3.1 MB <= 4 MB L2, K/V become L2-resident per XCD);
// each batch spans 4 XCDs x 32 q-tiles (balanced).  K-frag register
// prefetch + setprio unchanged.
// ---------------------------------------------------------------------------
__global__ __launch_bounds__(256, 4) void attn_kernel(
    const u16* __restrict__ Qf, const u16* __restrict__ Kf,
    const u16* __restrict__ Vfr, const u16* __restrict__ Vb,
    const int* __restrict__ seqlen, float* __restrict__ out) {
  __shared__ u16 Ps[4][16][40];
  __shared__ float Cacc[4][16][97];
  __shared__ float Cml[4][16][2];

  int bid = blockIdx.x;
  int x = bid & 7;                    // XCD
  int j = bid >> 3;                   // 0..127
  int q = j & 3;
  int bb = (x + 2 * q) & 7;           // 4 batches per XCD
  int bx = q * 32 + (j >> 2);         // q-tile 0..127
  int tid = threadIdx.x;
  int wid = tid >> 6, lane = tid & 63, ln = lane & 15, kg = lane >> 4;
  int n = seqlen[bb];
  int nkc = (n + 31) >> 5;

  size_t qt = (size_t)bb * 128 + bx;
  s16x8 aQ[3];
  #pragma unroll
  for (int kk = 0; kk < 3; ++kk)
    aQ[kk] = *(const s16x8*)&Qf[((qt * 3 + kk) * 64 + lane) * 8];

  float m[4], lsum[4];
  f32x4 acc[6];
  #pragma unroll
  for (int r = 0; r < 4; ++r) { m[r] = -1e30f; lsum[r] = 0.f; }
  #pragma unroll
  for (int nt = 0; nt < 6; ++nt) acc[nt] = (f32x4){0.f, 0.f, 0.f, 0.f};

  const u16* Kbb = Kf + (size_t)bb * 128 * 1536;
  s16x8 kf[6];
  {
    int k0 = (wid < nkc) ? wid : 0;
    const u16* kp = Kbb + (size_t)k0 * 3072 + lane * 8;
    #pragma unroll
    for (int i = 0; i < 6; ++i) kf[i] = *(const s16x8*)&kp[i * 512];
  }

  for (int kc = wid; kc < nkc; kc += 4) {
    int key0 = kc * 32;
    f32x4 s0 = (f32x4){0.f, 0.f, 0.f, 0.f};
    f32x4 s1 = (f32x4){0.f, 0.f, 0.f, 0.f};
    __builtin_amdgcn_s_setprio(1);
    #pragma unroll
    for (int kk = 0; kk < 3; ++kk) {
      s0 = __builtin_amdgcn_mfma_f32_16x16x32_bf16(aQ[kk], kf[kk], s0, 0, 0, 0);
      s1 = __builtin_amdgcn_mfma_f32_16x16x32_bf16(aQ[kk], kf[3 + kk], s1, 0, 0, 0);
    }
    __builtin_amdgcn_s_setprio(0);

    s16x8 kf2[6];
    {
      int kn = (kc + 4 < nkc) ? kc + 4 : 0;
      const u16* kp = Kbb + (size_t)kn * 3072 + lane * 8;
      #pragma unroll
      for (int i = 0; i < 6; ++i) kf2[i] = *(const s16x8*)&kp[i * 512];
    }

    bool v0 = (key0 + ln) < n;
    bool v1 = (key0 + 16 + ln) < n;
    float sv0[4], sv1[4], mx[4];
    #pragma unroll
    for (int r = 0; r < 4; ++r) {
      sv0[r] = v0 ? s0[r] * NORMS : -1e30f;
      sv1[r] = v1 ? s1[r] * NORMS : -1e30f;
      mx[r] = fmaxf(sv0[r], sv1[r]);
    }
    #pragma unroll
    for (int r = 0; r < 4; ++r) {
      mx[r] = fmaxf(mx[r], __shfl_xor(mx[r], 1, 16));
      mx[r] = fmaxf(mx[r], __shfl_xor(mx[r], 2, 16));
      mx[r] = fmaxf(mx[r], __shfl_xor(mx[r], 4, 16));
      mx[r] = fmaxf(mx[r], __shfl_xor(mx[r], 8, 16));
    }
    float p0[4], p1[4], rs[4];
    bool defer = __all((mx[0] <= m[0] + 8.f) && (mx[1] <= m[1] + 8.f) &&
                       (mx[2] <= m[2] + 8.f) && (mx[3] <= m[3] + 8.f));
    if (defer) {
      #pragma unroll
      for (int r = 0; r < 4; ++r) {
        p0[r] = __expf(sv0[r] - m[r]);
        p1[r] = __expf(sv1[r] - m[r]);
        rs[r] = p0[r] + p1[r];
      }
      #pragma unroll
      for (int r = 0; r < 4; ++r) {
        rs[r] += __shfl_xor(rs[r], 1, 16);
        rs[r] += __shfl_xor(rs[r], 2, 16);
        rs[r] += __shfl_xor(rs[r], 4, 16);
        rs[r] += __shfl_xor(rs[r], 8, 16);
        lsum[r] += rs[r];
      }
    } else {
      float fac[4];
      #pragma unroll
      for (int r = 0; r < 4; ++r) {
        float mn = fmaxf(m[r], mx[r]);
        fac[r] = __expf(m[r] - mn);
        p0[r] = __expf(sv0[r] - mn);
        p1[r] = __expf(sv1[r] - mn);
        rs[r] = p0[r] + p1[r];
        m[r] = mn;
      }
      #pragma unroll
      for (int r = 0; r < 4; ++r) {
        rs[r] += __shfl_xor(rs[r], 1, 16);
        rs[r] += __shfl_xor(rs[r], 2, 16);
        rs[r] += __shfl_xor(rs[r], 4, 16);
        rs[r] += __shfl_xor(rs[r], 8, 16);
        lsum[r] = lsum[r] * fac[r] + rs[r];
      }
      #pragma unroll
      for (int nt = 0; nt < 6; ++nt)
        #pragma unroll
        for (int r = 0; r < 4; ++r) acc[nt][r] *= fac[r];
    }

    u16* Pw = &Ps[wid][0][0];
    #pragma unroll
    for (int r = 0; r < 4; ++r) {
      Pw[(kg * 4 + r) * 40 + ln] = f2bf(p0[r]);
      Pw[(kg * 4 + r) * 40 + 16 + ln] = f2bf(p1[r]);
    }
    s16x8 pa = *(const s16x8*)&Pw[ln * 40 + kg * 8];

    const u16* vf = Vfr + (((size_t)bb * 64 + kc) * 6 * 64) * 8 + lane * 8;
    s16x8 bv[6];
    #pragma unroll
    for (int nt = 0; nt < 6; ++nt)
      bv[nt] = *(const s16x8*)&vf[(size_t)nt * 512];
    __builtin_amdgcn_s_setprio(1);
    #pragma unroll
    for (int nt = 0; nt < 6; ++nt)
      acc[nt] = __builtin_amdgcn_mfma_f32_16x16x32_bf16(pa, bv[nt], acc[nt], 0, 0, 0);
    __builtin_amdgcn_s_setprio(0);
    #pragma unroll
    for (int i = 0; i < 6; ++i) kf[i] = kf2[i];
  }

  #pragma unroll
  for (int nt = 0; nt < 6; ++nt)
    #pragma unroll
    for (int r = 0; r < 4; ++r)
      Cacc[wid][kg * 4 + r][nt * 16 + ln] = acc[nt][r];
  if (ln == 0) {
    #pragma unroll
    for (int r = 0; r < 4; ++r) {
      Cml[wid][kg * 4 + r][0] = m[r];
      Cml[wid][kg * 4 + r][1] = lsum[r];
    }
  }
  __syncthreads();

  size_t obase = ((size_t)bb * LSEQ + bx * 16) * 96;
  for (int i = tid; i < 1536; i += 256) {
    int row = i / 96;
    float mg = -1e30f;
    #pragma unroll
    for (int w = 0; w < 4; ++w) mg = fmaxf(mg, Cml[w][row][0]);
    float lg = 0.f, av = 0.f;
    #pragma unroll
    for (int w = 0; w < 4; ++w) {
      float e = __expf(Cml[w][row][0] - mg);
      lg += Cml[w][row][1] * e;
      av += Cacc[w][row][i - row * 96] * e;
    }
    out[obase + i] = av / lg + bf2f(Vb[obase + i]);
  }
}

// ---------------------------------------------------------------------------
extern "C" void kernel_launch(void* const* d_in, const int* in_sizes, int n_in,
                              void* d_out, int out_size, void* d_ws,
                              size_t ws_size, hipStream_t stream) {
  const float* plm   = (const float*)d_in[0];
  const float* evo   = (const float*)d_in[1];
  const int* seqlen  = (const int*)d_in[2];
  const float* q_w   = (const float*)d_in[3];
  const float* q_b   = (const float*)d_in[4];
  const float* k_w   = (const float*)d_in[5];
  const float* k_b   = (const float*)d_in[6];
  const float* v_w   = (const float*)d_in[7];
  const float* v_b   = (const float*)d_in[8];
  const float* cn3_w = (const float*)d_in[9];
  const float* cn3_b = (const float*)d_in[10];
  const float* cn5_w = (const float*)d_in[11];
  const float* cn5_b = (const float*)d_in[12];

  char* ws = (char*)d_ws;
  u16* wefff  = (u16*)(ws + 0);           // 491520
  float* beff = (float*)(ws + 491520);    // 512
  u16* qwf    = (u16*)(ws + 492032);      // 98304
  u16* vwf    = (u16*)(ws + 590336);      // 196608
  float* c3t  = (float*)(ws + 786944);    // 589824
  float* c5t  = (float*)(ws + 1376768);   // 983040
  u16* kw3f   = (u16*)(ws + 2359808);     // 18432
  u16* kw5f   = (u16*)(ws + 2378240);     // 18432
  u16* Qf     = (u16*)(ws + 2396672);     // 3145728
  u16* Kf     = (u16*)(ws + 5542400);     // 3145728
  u16* Vfr    = (u16*)(ws + 8688128);     // 3145728
  u16* Vb     = (u16*)(ws + 11833856);    // 3145728
  float* out  = (float*)d_out;

  prep1<<<2185, 256, 0, stream>>>(q_w, k_w, k_b, v_w, cn3_w, cn3_b, cn5_w,
                                  cn5_b, c3t, c5t, qwf, vwf, kw3f, kw5f, beff);
  prep2<<<40, 256, 0, stream>>>(c3t, c5t, kw3f, kw5f, k_w, wefff);
  proj_fused<<<512, 256, 0, stream>>>(evo, plm, qwf, vwf, wefff,
                                      q_b, beff, v_b, Qf, Kf, Vfr, Vb);
  attn_kernel<<<1024, 256, 0, stream>>>(Qf, Kf, Vfr, Vb, seqlen, out);
}

// Round 19
// 80.851 us; speedup vs baseline: 1.9737x; 1.0140x over previous
//
#include <hip/hip_runtime.h>

typedef unsigned short u16;
typedef unsigned int u32;
typedef float f32x4 __attribute__((ext_vector_type(4)));
typedef short s16x8 __attribute__((ext_vector_type(8)));

#define LSEQ 2048
#define QIN 512
#define VIN 1024
#define KCAT 704
#define KEFF 2560
#define NORMS 0.10206207261596575f  // 1/sqrt(96)

__device__ __forceinline__ u16 f2bf(float f) {
  u32 u = __float_as_uint(f);
  u = (u + 0x7fffu + ((u >> 16) & 1u)) >> 16;  // RNE
  return (u16)u;
}
__device__ __forceinline__ float bf2f(u16 v) {
  return __uint_as_float(((u32)v) << 16);
}

__device__ __forceinline__ s16x8 load8cvt(const float* __restrict__ p) {
  float4 a = *(const float4*)p;
  float4 b = *(const float4*)(p + 4);
  s16x8 r;
  r[0] = (short)f2bf(a.x); r[1] = (short)f2bf(a.y);
  r[2] = (short)f2bf(a.z); r[3] = (short)f2bf(a.w);
  r[4] = (short)f2bf(b.x); r[5] = (short)f2bf(b.y);
  r[6] = (short)f2bf(b.z); r[7] = (short)f2bf(b.w);
  return r;
}

__device__ __forceinline__ s16x8 cvt2x4(float4 a, float4 b) {
  s16x8 r;
  r[0] = (short)f2bf(a.x); r[1] = (short)f2bf(a.y);
  r[2] = (short)f2bf(a.z); r[3] = (short)f2bf(a.w);
  r[4] = (short)f2bf(b.x); r[5] = (short)f2bf(b.y);
  r[6] = (short)f2bf(b.z); r[7] = (short)f2bf(b.w);
  return r;
}

// Fragment-linear index for a weight matrix W[N=96][K]:
// element W[o][k] -> ((kc*6 + nt)*64 + kg*16 + ln)*8 + j
__device__ __forceinline__ size_t wfrag_idx(int o, int k) {
  int kc = k >> 5, kg = (k >> 3) & 3, j = k & 7;
  int nt = o >> 4, ln = o & 15;
  return ((size_t)(kc * 6 + nt) * 64 + kg * 16 + ln) * 8 + j;
}

// ---------------------------------------------------------------------------
// Kernel 1 (prep1): conv-weight transposes now LDS-TILED (coalesced both
// sides): block = one 16-wide c-tile; read 96 contiguous source segments,
// write j-innermost coalesced.  Plus q_w/v_w -> frag bf16, kw frags, b_eff.
// blocks: [0,32) c3t tiles, [32,64) c5t tiles, [64,256) qwf,
//         [256,640) vwf, [640,712) kw3f/kw5f, 712 b_eff.
// ---------------------------------------------------------------------------
__global__ __launch_bounds__(256) void prep1(
    const float* __restrict__ q_w, const float* __restrict__ k_w,
    const float* __restrict__ k_b, const float* __restrict__ v_w,
    const float* __restrict__ cn3_w, const float* __restrict__ cn3_b,
    const float* __restrict__ cn5_w, const float* __restrict__ cn5_b,
    float* __restrict__ c3t, float* __restrict__ c5t,
    u16* __restrict__ qwf, u16* __restrict__ vwf,
    u16* __restrict__ kw3f, u16* __restrict__ kw5f,
    float* __restrict__ beff) {
  __shared__ float T[7680];
  int blk = blockIdx.x, tid = threadIdx.x;
  if (blk < 32) {                        // c3t tile: c0=blk*16, 4608 elems
    int c0 = blk * 16;
    #pragma unroll
    for (int p = 0; p < 18; ++p) {
      int idx = tid + p * 256;           // j*48 + r, r = cc*3 + t
      int j = idx / 48, r = idx - j * 48;
      T[idx] = cn3_w[j * 1536 + c0 * 3 + r];
    }
    __syncthreads();
    #pragma unroll
    for (int p = 0; p < 18; ++p) {
      int o = tid + p * 256;             // t*1536 + cc*96 + j
      int t = o / 1536, rem = o - t * 1536;
      int cc = rem / 96, j = rem - cc * 96;
      c3t[(size_t)(t * 512 + c0 + cc) * 96 + j] = T[j * 48 + cc * 3 + t];
    }
  } else if (blk < 64) {                 // c5t tile: 7680 elems
    int c0 = (blk - 32) * 16;
    #pragma unroll
    for (int p = 0; p < 30; ++p) {
      int idx = tid + p * 256;           // j*80 + r, r = cc*5 + t
      int j = idx / 80, r = idx - j * 80;
      T[idx] = cn5_w[j * 2560 + c0 * 5 + r];
    }
    __syncthreads();
    #pragma unroll
    for (int p = 0; p < 30; ++p) {
      int o = tid + p * 256;             // t*1536 + cc*96 + j
      int t = o / 1536, rem = o - t * 1536;
      int cc = rem / 96, j = rem - cc * 96;
      c5t[(size_t)(t * 512 + c0 + cc) * 96 + j] = T[j * 80 + cc * 5 + t];
    }
  } else if (blk < 256) {                // qwf: 49152
    int e = (blk - 64) * 256 + tid;
    int o = e >> 9, k = e & 511;
    qwf[wfrag_idx(o, k)] = f2bf(q_w[e]);
  } else if (blk < 640) {                // vwf: 98304
    int e = (blk - 256) * 256 + tid;
    int o = e >> 10, k = e & 1023;
    vwf[wfrag_idx(o, k)] = f2bf(v_w[e]);
  } else if (blk < 712) {                // kw3f + kw5f: 2*9216
    int e = (blk - 640) * 256 + tid;
    int half = e / 9216;
    int i = e - half * 9216;
    int o = i / 96, j = i - o * 96;
    float v = k_w[o * KCAT + (half ? 608 : 512) + j];
    size_t di = ((size_t)((j >> 5) * 6 + (o >> 4)) * 64 +
                 ((j >> 3) & 3) * 16 + (o & 15)) * 8 + (j & 7);
    (half ? kw5f : kw3f)[di] = f2bf(v);
  } else {                               // b_eff
    if (tid < 96) {
      const float* kwo = k_w + tid * KCAT;
      float b = k_b[tid];
      for (int j = 0; j < 96; ++j)
        b += kwo[512 + j] * cn3_b[j] + kwo[608 + j] * cn5_b[j];
      beff[tid] = b;
    }
  }
}

// ---------------------------------------------------------------------------
// Kernel 2 (prep2): W_eff fold as a GEMM (M=2560, N=96, K=96).
// ---------------------------------------------------------------------------
__global__ __launch_bounds__(256) void prep2(
    const float* __restrict__ c3t, const float* __restrict__ c5t,
    const u16* __restrict__ kw3f, const u16* __restrict__ kw5f,
    const float* __restrict__ k_w, u16* __restrict__ wefff) {
  __shared__ float Ls[4][16][100];
  int blk = blockIdx.x, tid = threadIdx.x;
  int wid = tid >> 6, lane = tid & 63, ln = lane & 15, kg = lane >> 4;
  int k = blk * 64 + wid * 16 + ln;
  bool c3ok = (k >= 512) && (k < 2048);
  const float* a5 = c5t + (size_t)k * 96;
  const float* a3 = c3t + (size_t)(c3ok ? k - 512 : 0) * 96;
  f32x4 acc[6];
  #pragma unroll
  for (int nt = 0; nt < 6; ++nt) acc[nt] = (f32x4){0.f, 0.f, 0.f, 0.f};
  #pragma unroll
  for (int jc = 0; jc < 3; ++jc) {
    s16x8 aa5 = load8cvt(a5 + jc * 32 + kg * 8);
    s16x8 aa3 = (s16x8){0, 0, 0, 0, 0, 0, 0, 0};
    if (c3ok) aa3 = load8cvt(a3 + jc * 32 + kg * 8);
    const u16* b5 = kw5f + (size_t)jc * 3072 + lane * 8;
    const u16* b3 = kw3f + (size_t)jc * 3072 + lane * 8;
    #pragma unroll
    for (int nt = 0; nt < 6; ++nt) {
      acc[nt] = __builtin_amdgcn_mfma_f32_16x16x32_bf16(
          aa5, *(const s16x8*)&b5[nt * 512], acc[nt], 0, 0, 0);
      acc[nt] = __builtin_amdgcn_mfma_f32_16x16x32_bf16(
          aa3, *(const s16x8*)&b3[nt * 512], acc[nt], 0, 0, 0);
    }
  }
  #pragma unroll
  for (int nt = 0; nt < 6; ++nt)
    #pragma unroll
    for (int r = 0; r < 4; ++r)
      Ls[wid][kg * 4 + r][nt * 16 + ln] = acc[nt][r];
  asm volatile("s_waitcnt lgkmcnt(0)" ::: "memory");
  #pragma unroll
  for (int sl = 0; sl < 3; ++sl) {
    int slot = sl * 64 + lane;
    int o = slot >> 1, rc = slot & 1;
    int k0 = blk * 64 + wid * 16 + rc * 8;
    int t = k0 >> 9, cbase = k0 & 511;
    s16x8 ov;
    #pragma unroll
    for (int e = 0; e < 8; ++e) {
      float v = Ls[wid][rc * 8 + e][o];
      if (t == 2) v += k_w[o * KCAT + cbase + e];
      ov[e] = (short)f2bf(v);
    }
    *(s16x8*)&wefff[((size_t)((k0 >> 5) * 6 + (o >> 4)) * 64 +
                     ((k0 >> 3) & 3) * 16 + (o & 15)) * 8] = ov;
  }
}

// ---------------------------------------------------------------------------
// Kernel 3: Q+K-conv and V projections fused (round-17/18 structure).
// Linear 512-grid: QK = bids [0,256), V = bids [256,512) so co-resident
// pairs (bid, bid+256) are one compute-bound QK + one memory-bound V block.
// ---------------------------------------------------------------------------
__global__ __launch_bounds__(256, 2) void proj_fused(
    const float* __restrict__ evo, const float* __restrict__ plm,
    const u16* __restrict__ qwf, const u16* __restrict__ vwf,
    const u16* __restrict__ wefff, const float* __restrict__ q_b,
    const float* __restrict__ beff, const float* __restrict__ v_b,
    u16* __restrict__ Qf, u16* __restrict__ Kf,
    u16* __restrict__ Vfr, u16* __restrict__ Vb) {
  __shared__ u16 At[2 * 68 * 72];     // 19584 B, A double-buffer
  __shared__ u16 LBS[18432];          // 36864 B, B single-buffer (+ Ls alias)
  float* Ls = (float*)LBS;            // epilogue scratch: [wid*1600 + r*100 + c]
  int bid = blockIdx.x;               // 0..511 linear
  int tid = threadIdx.x;
  int wid = tid >> 6, lane = tid & 63, ln = lane & 15, kg = lane >> 4;
  int srow = tid >> 2, spart = tid & 3;

  if (bid < 256) {
    // ---------------- QK path (A = evo, 68-row halo tile) ----------------
    int bx = bid & 31, bb = bid >> 5;
    int r0 = bx * 64;
    const float* xb = evo + (size_t)bb * LSEQ * QIN;
    bool halo = tid < 16;
    int hrow = 64 + (tid >> 2);

    float4 ra0, ra1, ra2, ra3, rb0, rb1, rb2, rb3;
    auto LOADS = [&](int s) {
      int g = r0 - 2 + srow;
      if (g >= 0 && g < LSEQ) {
        const float* p = xb + (size_t)g * QIN + s * 64 + spart * 16;
        ra0 = *(const float4*)p;       ra1 = *(const float4*)(p + 4);
        ra2 = *(const float4*)(p + 8); ra3 = *(const float4*)(p + 12);
      } else {
        ra0 = ra1 = ra2 = ra3 = make_float4(0.f, 0.f, 0.f, 0.f);
      }
      if (halo) {
        int g2 = r0 - 2 + hrow;
        if (g2 < LSEQ) {
          const float* p = xb + (size_t)g2 * QIN + s * 64 + spart * 16;
          rb0 = *(const float4*)p;       rb1 = *(const float4*)(p + 4);
          rb2 = *(const float4*)(p + 8); rb3 = *(const float4*)(p + 12);
        } else {
          rb0 = rb1 = rb2 = rb3 = make_float4(0.f, 0.f, 0.f, 0.f);
        }
      }
    };
    auto WRITES = [&](int buf) {
      u16* d = &At[(buf * 68 + srow) * 72 + spart * 16];
      *(s16x8*)d = cvt2x4(ra0, ra1);
      *(s16x8*)(d + 8) = cvt2x4(ra2, ra3);
      if (halo) {
        u16* d2 = &At[(buf * 68 + hrow) * 72 + spart * 16];
        *(s16x8*)d2 = cvt2x4(rb0, rb1);
        *(s16x8*)(d2 + 8) = cvt2x4(rb2, rb3);
      }
    };

    // B staging: 36 KB = [Q, tap0..tap4][kcg slice 6KB]; 9x16B per thread
    s16x8 br[9];
    auto LOADB = [&](int kcg) {
      #pragma unroll
      for (int j = 0; j < 9; ++j) {
        int idx = tid + j * 256;
        int chunk = idx / 384;           // 0=Q, 1..5=taps
        int off = idx - chunk * 384;
        const u16* src = (chunk == 0)
            ? qwf + (size_t)kcg * 3072 + off * 8
            : wefff + (size_t)(chunk - 1) * 49152 + (size_t)kcg * 3072 + off * 8;
        br[j] = *(const s16x8*)src;
      }
    };
    auto STOREB = [&]() {
      #pragma unroll
      for (int j = 0; j < 9; ++j) {
        int idx = tid + j * 256;
        *(s16x8*)&LBS[idx * 8] = br[j];
      }
    };

    f32x4 accQ[6], accK[6];
    #pragma unroll
    for (int nt = 0; nt < 6; ++nt) {
      accQ[nt] = (f32x4){0.f, 0.f, 0.f, 0.f};
      accK[nt] = (f32x4){0.f, 0.f, 0.f, 0.f};
    }

    LOADS(0);
    LOADB(0);
    WRITES(0);
    STOREB();
    __syncthreads();
    int cur = 0;
    for (int s = 0; s < 8; ++s) {
      if (s < 7) LOADS(s + 1);
      #pragma unroll
      for (int cc = 0; cc < 2; ++cc) {
        int kcg = s * 2 + cc;
        bool havenext = kcg < 15;
        if (havenext) LOADB(kcg + 1);
        const u16* arow = &At[(cur * 68 + wid * 16 + ln) * 72 + cc * 32 + kg * 8];
        s16x8 aQ  = *(const s16x8*)&arow[2 * 72];
        s16x8 aK0 = *(const s16x8*)&arow[0];
        s16x8 aK1 = *(const s16x8*)&arow[1 * 72];
        s16x8 aK3 = *(const s16x8*)&arow[3 * 72];
        s16x8 aK4 = *(const s16x8*)&arow[4 * 72];
        const u16* lb = LBS + lane * 8;
        s16x8 bfr[6];
        #pragma unroll
        for (int i = 0; i < 6; ++i)
          bfr[i] = *(const s16x8*)&lb[i * 512];
        #pragma unroll
        for (int i = 0; i < 6; ++i)
          accQ[i] = __builtin_amdgcn_mfma_f32_16x16x32_bf16(
              aQ, bfr[i], accQ[i], 0, 0, 0);
        #pragma unroll
        for (int t = 0; t < 5; ++t) {
          s16x8 bf2[6];
          #pragma unroll
          for (int i = 0; i < 6; ++i)
            bf2[i] = *(const s16x8*)&lb[(1 + t) * 3072 + i * 512];
          s16x8 aK = (t == 0) ? aK0 : (t == 1) ? aK1 : (t == 2) ? aQ
                   : (t == 3) ? aK3 : aK4;
          #pragma unroll
          for (int i = 0; i < 6; ++i)
            accK[i] = __builtin_amdgcn_mfma_f32_16x16x32_bf16(
                aK, bf2[i], accK[i], 0, 0, 0);
        }
        __syncthreads();                 // everyone done reading LBS
        if (havenext) STOREB();
        if (cc == 1 && s < 7) WRITES(cur ^ 1);
        __syncthreads();                 // B(next) + A(next) published
      }
      if (s < 7) cur ^= 1;
    }

    size_t qt = (size_t)bb * 128 + bx * 4 + wid;
    #pragma unroll
    for (int nt = 0; nt < 6; ++nt)
      #pragma unroll
      for (int r = 0; r < 4; ++r)
        Ls[wid * 1600 + (kg * 4 + r) * 100 + nt * 16 + ln] = accQ[nt][r];
    asm volatile("s_waitcnt lgkmcnt(0)" ::: "memory");
    #pragma unroll
    for (int sl = 0; sl < 3; ++sl) {
      int slot = sl * 64 + lane;
      int r = slot / 12, cg = slot % 12;
      s16x8 ov;
      #pragma unroll
      for (int e = 0; e < 8; ++e) {
        int c = cg * 8 + e;
        ov[e] = (short)f2bf(Ls[wid * 1600 + r * 100 + c] + q_b[c]);
      }
      *(s16x8*)&Qf[((qt * 3 + (cg >> 2)) * 64 + (cg & 3) * 16 + r) * 8] = ov;
    }
    asm volatile("s_waitcnt lgkmcnt(0) vmcnt(0)" ::: "memory");
    #pragma unroll
    for (int nt = 0; nt < 6; ++nt)
      #pragma unroll
      for (int r = 0; r < 4; ++r)
        Ls[wid * 1600 + (kg * 4 + r) * 100 + nt * 16 + ln] = accK[nt][r];
    asm volatile("s_waitcnt lgkmcnt(0)" ::: "memory");
    #pragma unroll
    for (int sl = 0; sl < 3; ++sl) {
      int slot = sl * 64 + lane;
      int r = slot / 12, cg = slot % 12;
      s16x8 ov;
      #pragma unroll
      for (int e = 0; e < 8; ++e) {
        int c = cg * 8 + e;
        ov[e] = (short)f2bf(Ls[wid * 1600 + r * 100 + c] + beff[c]);
      }
      *(s16x8*)&Kf[((qt * 3 + (cg >> 2)) * 64 + (cg & 3) * 16 + r) * 8] = ov;
    }
  } else {
    // ---------------- V path (A = plm, 64-row tile, K=1024) ----------------
    int i = bid - 256;
    int bx = i & 31, bb = i >> 5;
    const float* xb = plm + ((size_t)bb * LSEQ + bx * 64) * VIN;
    float4 ra0, ra1, ra2, ra3;
    auto LOADS = [&](int s) {
      const float* p = xb + (size_t)srow * VIN + s * 64 + spart * 16;
      ra0 = *(const float4*)p;       ra1 = *(const float4*)(p + 4);
      ra2 = *(const float4*)(p + 8); ra3 = *(const float4*)(p + 12);
    };
    auto WRITES = [&](int buf) {
      u16* d = &At[(buf * 68 + srow) * 72 + spart * 16];
      *(s16x8*)d = cvt2x4(ra0, ra1);
      *(s16x8*)(d + 8) = cvt2x4(ra2, ra3);
    };
    // B staging: 12 KB per s-step (2 kcg, contiguous in vwf); 3x16B/thread
    s16x8 br[3];
    auto LOADB = [&](int s) {
      #pragma unroll
      for (int j = 0; j < 3; ++j) {
        int idx = tid + j * 256;
        br[j] = *(const s16x8*)(vwf + (size_t)s * 6144 + idx * 8);
      }
    };
    auto STOREB = [&]() {
      #pragma unroll
      for (int j = 0; j < 3; ++j) {
        int idx = tid + j * 256;
        *(s16x8*)&LBS[idx * 8] = br[j];
      }
    };

    f32x4 acc[6];
    #pragma unroll
    for (int nt = 0; nt < 6; ++nt) acc[nt] = (f32x4){0.f, 0.f, 0.f, 0.f};

    LOADS(0);
    LOADB(0);
    WRITES(0);
    STOREB();
    __syncthreads();
    int cur = 0;
    for (int s = 0; s < 16; ++s) {
      if (s < 15) {
        LOADS(s + 1);
        LOADB(s + 1);
      }
      #pragma unroll
      for (int cc = 0; cc < 2; ++cc) {
        s16x8 a = *(const s16x8*)&At[(cur * 68 + wid * 16 + ln) * 72 +
                                     cc * 32 + kg * 8];
        const u16* lb = LBS + cc * 3072 + lane * 8;
        s16x8 bfr[6];
        #pragma unroll
        for (int nt = 0; nt < 6; ++nt)
          bfr[nt] = *(const s16x8*)&lb[nt * 512];
        #pragma unroll
        for (int nt = 0; nt < 6; ++nt)
          acc[nt] = __builtin_amdgcn_mfma_f32_16x16x32_bf16(
              a, bfr[nt], acc[nt], 0, 0, 0);
      }
      __syncthreads();                   // done reading LBS + At[cur]
      if (s < 15) {
        STOREB();
        WRITES(cur ^ 1);
      }
      __syncthreads();                   // B(s+1) + A(s+1) published
      if (s < 15) cur ^= 1;
    }

    #pragma unroll
    for (int nt = 0; nt < 6; ++nt)
      #pragma unroll
      for (int r = 0; r < 4; ++r)
        Ls[wid * 1600 + (kg * 4 + r) * 100 + nt * 16 + ln] = acc[nt][r];
    asm volatile("s_waitcnt lgkmcnt(0)" ::: "memory");
    #pragma unroll
    for (int sl = 0; sl < 3; ++sl) {
      int slot = sl * 64 + lane;
      int r = slot / 12, cg = slot % 12;
      s16x8 ov;
      #pragma unroll
      for (int e = 0; e < 8; ++e) {
        int c = cg * 8 + e;
        ov[e] = (short)f2bf(Ls[wid * 1600 + r * 100 + c] + v_b[c]);
      }
      *(s16x8*)&Vb[((size_t)bb * LSEQ + bx * 64 + wid * 16 + r) * 96 + cg * 8] = ov;
    }
    #pragma unroll
    for (int sl = 0; sl < 3; ++sl) {
      int slot = sl * 64 + lane;
      int c = slot >> 1, rc = slot & 1;
      int key0 = bx * 64 + wid * 16 + rc * 8;
      s16x8 fv;
      #pragma unroll
      for (int e = 0; e < 8; ++e)
        fv[e] = (short)f2bf(Ls[wid * 1600 + (rc * 8 + e) * 100 + c] + v_b[c]);
      *(s16x8*)&Vfr[(((size_t)bb * 64 + (key0 >> 5)) * 6 + (c >> 4)) * 512 +
                    (((key0 >> 3) & 3) * 16 + (c & 15)) * 8] = fv;
    }
  }
}

// ---------------------------------------------------------------------------
// Kernel 4: flash attention + "+V".  XCD-resident batch mapping (4 batches
// per XCD, K/V L2-resident) + K-frag register prefetch + setprio.
// ---------------------------------------------------------------------------
__global__ __launch_bounds__(256, 4) void attn_kernel(
    const u16* __restrict__ Qf, const u16* __restrict__ Kf,
    const u16* __restrict__ Vfr, const u16* __restrict__ Vb,
    const int* __restrict__ seqlen, float* __restrict__ out) {
  __shared__ u16 Ps[4][16][40];
  __shared__ float Cacc[4][16][97];
  __shared__ float Cml[4][16][2];

  int bid = blockIdx.x;
  int x = bid & 7;                    // XCD
  int j = bid >> 3;                   // 0..127
  int q = j & 3;
  int bb = (x + 2 * q) & 7;           // 4 batches per XCD
  int bx = q * 32 + (j >> 2);         // q-tile 0..127
  int tid = threadIdx.x;
  int wid = tid >> 6, lane = tid & 63, ln = lane & 15, kg = lane >> 4;
  int n = seqlen[bb];
  int nkc = (n + 31) >> 5;

  size_t qt = (size_t)bb * 128 + bx;
  s16x8 aQ[3];
  #pragma unroll
  for (int kk = 0; kk < 3; ++kk)
    aQ[kk] = *(const s16x8*)&Qf[((qt * 3 + kk) * 64 + lane) * 8];

  float m[4], lsum[4];
  f32x4 acc[6];
  #pragma unroll
  for (int r = 0; r < 4; ++r) { m[r] = -1e30f; lsum[r] = 0.f; }
  #pragma unroll
  for (int nt = 0; nt < 6; ++nt) acc[nt] = (f32x4){0.f, 0.f, 0.f, 0.f};

  const u16* Kbb = Kf + (size_t)bb * 128 * 1536;
  s16x8 kf[6];
  {
    int k0 = (wid < nkc) ? wid : 0;
    const u16* kp = Kbb + (size_t)k0 * 3072 + lane * 8;
    #pragma unroll
    for (int i = 0; i < 6; ++i) kf[i] = *(const s16x8*)&kp[i * 512];
  }

  for (int kc = wid; kc < nkc; kc += 4) {
    int key0 = kc * 32;
    f32x4 s0 = (f32x4){0.f, 0.f, 0.f, 0.f};
    f32x4 s1 = (f32x4){0.f, 0.f, 0.f, 0.f};
    __builtin_amdgcn_s_setprio(1);
    #pragma unroll
    for (int kk = 0; kk < 3; ++kk) {
      s0 = __builtin_amdgcn_mfma_f32_16x16x32_bf16(aQ[kk], kf[kk], s0, 0, 0, 0);
      s1 = __builtin_amdgcn_mfma_f32_16x16x32_bf16(aQ[kk], kf[3 + kk], s1, 0, 0, 0);
    }
    __builtin_amdgcn_s_setprio(0);

    s16x8 kf2[6];
    {
      int kn = (kc + 4 < nkc) ? kc + 4 : 0;
      const u16* kp = Kbb + (size_t)kn * 3072 + lane * 8;
      #pragma unroll
      for (int i = 0; i < 6; ++i) kf2[i] = *(const s16x8*)&kp[i * 512];
    }

    bool v0 = (key0 + ln) < n;
    bool v1 = (key0 + 16 + ln) < n;
    float sv0[4], sv1[4], mx[4];
    #pragma unroll
    for (int r = 0; r < 4; ++r) {
      sv0[r] = v0 ? s0[r] * NORMS : -1e30f;
      sv1[r] = v1 ? s1[r] * NORMS : -1e30f;
      mx[r] = fmaxf(sv0[r], sv1[r]);
    }
    #pragma unroll
    for (int r = 0; r < 4; ++r) {
      mx[r] = fmaxf(mx[r], __shfl_xor(mx[r], 1, 16));
      mx[r] = fmaxf(mx[r], __shfl_xor(mx[r], 2, 16));
      mx[r] = fmaxf(mx[r], __shfl_xor(mx[r], 4, 16));
      mx[r] = fmaxf(mx[r], __shfl_xor(mx[r], 8, 16));
    }
    float p0[4], p1[4], rs[4];
    bool defer = __all((mx[0] <= m[0] + 8.f) && (mx[1] <= m[1] + 8.f) &&
                       (mx[2] <= m[2] + 8.f) && (mx[3] <= m[3] + 8.f));
    if (defer) {
      #pragma unroll
      for (int r = 0; r < 4; ++r) {
        p0[r] = __expf(sv0[r] - m[r]);
        p1[r] = __expf(sv1[r] - m[r]);
        rs[r] = p0[r] + p1[r];
      }
      #pragma unroll
      for (int r = 0; r < 4; ++r) {
        rs[r] += __shfl_xor(rs[r], 1, 16);
        rs[r] += __shfl_xor(rs[r], 2, 16);
        rs[r] += __shfl_xor(rs[r], 4, 16);
        rs[r] += __shfl_xor(rs[r], 8, 16);
        lsum[r] += rs[r];
      }
    } else {
      float fac[4];
      #pragma unroll
      for (int r = 0; r < 4; ++r) {
        float mn = fmaxf(m[r], mx[r]);
        fac[r] = __expf(m[r] - mn);
        p0[r] = __expf(sv0[r] - mn);
        p1[r] = __expf(sv1[r] - mn);
        rs[r] = p0[r] + p1[r];
        m[r] = mn;
      }
      #pragma unroll
      for (int r = 0; r < 4; ++r) {
        rs[r] += __shfl_xor(rs[r], 1, 16);
        rs[r] += __shfl_xor(rs[r], 2, 16);
        rs[r] += __shfl_xor(rs[r], 4, 16);
        rs[r] += __shfl_xor(rs[r], 8, 16);
        lsum[r] = lsum[r] * fac[r] + rs[r];
      }
      #pragma unroll
      for (int nt = 0; nt < 6; ++nt)
        #pragma unroll
        for (int r = 0; r < 4; ++r) acc[nt][r] *= fac[r];
    }

    u16* Pw = &Ps[wid][0][0];
    #pragma unroll
    for (int r = 0; r < 4; ++r) {
      Pw[(kg * 4 + r) * 40 + ln] = f2bf(p0[r]);
      Pw[(kg * 4 + r) * 40 + 16 + ln] = f2bf(p1[r]);
    }
    s16x8 pa = *(const s16x8*)&Pw[ln * 40 + kg * 8];

    const u16* vf = Vfr + (((size_t)bb * 64 + kc) * 6 * 64) * 8 + lane * 8;
    s16x8 bv[6];
    #pragma unroll
    for (int nt = 0; nt < 6; ++nt)
      bv[nt] = *(const s16x8*)&vf[(size_t)nt * 512];
    __builtin_amdgcn_s_setprio(1);
    #pragma unroll
    for (int nt = 0; nt < 6; ++nt)
      acc[nt] = __builtin_amdgcn_mfma_f32_16x16x32_bf16(pa, bv[nt], acc[nt], 0, 0, 0);
    __builtin_amdgcn_s_setprio(0);
    #pragma unroll
    for (int i = 0; i < 6; ++i) kf[i] = kf2[i];
  }

  #pragma unroll
  for (int nt = 0; nt < 6; ++nt)
    #pragma unroll
    for (int r = 0; r < 4; ++r)
      Cacc[wid][kg * 4 + r][nt * 16 + ln] = acc[nt][r];
  if (ln == 0) {
    #pragma unroll
    for (int r = 0; r < 4; ++r) {
      Cml[wid][kg * 4 + r][0] = m[r];
      Cml[wid][kg * 4 + r][1] = lsum[r];
    }
  }
  __syncthreads();

  size_t obase = ((size_t)bb * LSEQ + bx * 16) * 96;
  for (int i = tid; i < 1536; i += 256) {
    int row = i / 96;
    float mg = -1e30f;
    #pragma unroll
    for (int w = 0; w < 4; ++w) mg = fmaxf(mg, Cml[w][row][0]);
    float lg = 0.f, av = 0.f;
    #pragma unroll
    for (int w = 0; w < 4; ++w) {
      float e = __expf(Cml[w][row][0] - mg);
      lg += Cml[w][row][1] * e;
      av += Cacc[w][row][i - row * 96] * e;
    }
    out[obase + i] = av / lg + bf2f(Vb[obase + i]);
  }
}

// ---------------------------------------------------------------------------
extern "C" void kernel_launch(void* const* d_in, const int* in_sizes, int n_in,
                              void* d_out, int out_size, void* d_ws,
                              size_t ws_size, hipStream_t stream) {
  const float* plm   = (const float*)d_in[0];
  const float* evo   = (const float*)d_in[1];
  const int* seqlen  = (const int*)d_in[2];
  const float* q_w   = (const float*)d_in[3];
  const float* q_b   = (const float*)d_in[4];
  const float* k_w   = (const float*)d_in[5];
  const float* k_b   = (const float*)d_in[6];
  const float* v_w   = (const float*)d_in[7];
  const float* v_b   = (const float*)d_in[8];
  const float* cn3_w = (const float*)d_in[9];
  const float* cn3_b = (const float*)d_in[10];
  const float* cn5_w = (const float*)d_in[11];
  const float* cn5_b = (const float*)d_in[12];

  char* ws = (char*)d_ws;
  u16* wefff  = (u16*)(ws + 0);           // 491520
  float* beff = (float*)(ws + 491520);    // 512
  u16* qwf    = (u16*)(ws + 492032);      // 98304
  u16* vwf    = (u16*)(ws + 590336);      // 196608
  float* c3t  = (float*)(ws + 786944);    // 589824
  float* c5t  = (float*)(ws + 1376768);   // 983040
  u16* kw3f   = (u16*)(ws + 2359808);     // 18432
  u16* kw5f   = (u16*)(ws + 2378240);     // 18432
  u16* Qf     = (u16*)(ws + 2396672);     // 3145728
  u16* Kf     = (u16*)(ws + 5542400);     // 3145728
  u16* Vfr    = (u16*)(ws + 8688128);     // 3145728
  u16* Vb     = (u16*)(ws + 11833856);    // 3145728
  float* out  = (float*)d_out;

  prep1<<<713, 256, 0, stream>>>(q_w, k_w, k_b, v_w, cn3_w, cn3_b, cn5_w,
                                 cn5_b, c3t, c5t, qwf, vwf, kw3f, kw5f, beff);
  prep2<<<40, 256, 0, stream>>>(c3t, c5t, kw3f, kw5f, k_w, wefff);
  proj_fused<<<512, 256, 0, stream>>>(evo, plm, qwf, vwf, wefff,
                                      q_b, beff, v_b, Qf, Kf, Vfr, Vb);
  attn_kernel<<<1024, 256, 0, stream>>>(Qf, Kf, Vfr, Vb, seqlen, out);
}